// Round 2
// baseline (1201.557 us; speedup 1.0000x reference)
//
#include <hip/hip_runtime.h>
#include <hip/hip_bf16.h>
#include <math.h>

// DeepSeekV3-style block: rmsnorm -> MLA attn -> residual -> rmsnorm -> MoE -> residual
// B=2 S=2048 D=1024 H=16 HD=64 R=256 E=8 K=2 MH=256
//
// Precision strategy (round 2): the router's top-2 over sigmoid(rmsnorm(xmid)@wr) is
// discrete — any xmid error ~1e-3 flips experts on near-tie tokens (absmax ~0.15).
// So the whole attention path (x1 -> q,c,k,v -> attn -> @wo -> xmid) runs in
// "emulated fp32": every bf16 value is a (hi,lo) bf16 pair, every MFMA product uses
// 3 terms (hi*hi + hi*lo + lo*hi), f32 accumulate => ~1e-5 relative accuracy.
// MoE compute path stays plain bf16 (smooth error ~1e-3 << 0.1 threshold).

typedef __attribute__((ext_vector_type(8))) short short8;
typedef __attribute__((ext_vector_type(4))) float f32x4;

static __device__ __forceinline__ float bf2f(short s) {
  union { unsigned u; float f; } c; c.u = ((unsigned)(unsigned short)s) << 16; return c.f;
}
static __device__ __forceinline__ short f2bf(float f) {
  __hip_bfloat16 h = __float2bfloat16(f);
  short s; __builtin_memcpy(&s, &h, sizeof(s)); return s;
}
static __device__ __forceinline__ void split2(float v, short& hi, short& lo) {
  hi = f2bf(v); lo = f2bf(v - bf2f(hi));
}

// ---------------- RoPE inv-freq table, bit-faithful to numpy f32 -------------------------
// numpy: t = powf(10000, j/32) (correctly rounded in glibc), inv = 1.0f/t.
// Emulate with double pow -> f32 (correctly rounded), then f32 divide.
__global__ void invtab_kernel(float* __restrict__ tab) {
  int j = threadIdx.x;
  if (j < 32) {
    float t = (float)pow(10000.0, (double)j * (1.0 / 32.0));
    tab[j] = 1.0f / t;
  }
}

// ---------------- rmsnorm: f32 in -> bf16 hi (+optional lo, invrms, f32 copy) ------------
__global__ __launch_bounds__(256) void rmsnorm_kernel(
    const float* __restrict__ in, const float* __restrict__ w,
    short* __restrict__ outH, short* __restrict__ outL,
    float* __restrict__ invrms, float* __restrict__ cpy)
{
  int row = blockIdx.x, tid = threadIdx.x;
  const float4* xv = (const float4*)(in + (size_t)row * 1024);
  float4 v = xv[tid];
  float ss = v.x*v.x + v.y*v.y + v.z*v.z + v.w*v.w;
  #pragma unroll
  for (int off = 32; off > 0; off >>= 1) ss += __shfl_down(ss, off);
  __shared__ float wsum[4];
  if ((tid & 63) == 0) wsum[tid >> 6] = ss;
  __syncthreads();
  float inv = rsqrtf((wsum[0] + wsum[1] + wsum[2] + wsum[3]) * (1.0f/1024.0f) + 1e-6f);
  float4 wv = ((const float4*)w)[tid];
  size_t base = (size_t)row * 1024 + (size_t)tid * 4;
  float r[4] = { v.x*inv*wv.x, v.y*inv*wv.y, v.z*inv*wv.z, v.w*inv*wv.w };
  #pragma unroll
  for (int j = 0; j < 4; ++j) {
    short hi, lo; split2(r[j], hi, lo);
    outH[base + j] = hi;
    if (outL) outL[base + j] = lo;
  }
  if (cpy) ((float4*)cpy)[(size_t)row * 256 + tid] = v;
  if (invrms && tid == 0) invrms[row] = inv;
}

// ---------------- transpose+convert: f32 (K,N) -> bf16 (N,K) hi(/lo), batched z ----------
template<bool SPLIT>
__global__ __launch_bounds__(256) void transpose_conv_kernel(
    const float* __restrict__ in, short* __restrict__ outH, short* __restrict__ outL,
    int K, int N)
{
  __shared__ float tile[32][33];
  size_t boff = (size_t)blockIdx.z * K * N;
  const float* ip = in + boff;
  int bn = blockIdx.x * 32, bk = blockIdx.y * 32;
  int tx = threadIdx.x & 31, ty = threadIdx.x >> 5;
  #pragma unroll
  for (int i = 0; i < 32; i += 8)
    tile[ty + i][tx] = ip[(size_t)(bk + ty + i) * N + bn + tx];
  __syncthreads();
  #pragma unroll
  for (int i = 0; i < 32; i += 8) {
    float v = tile[tx][ty + i];
    size_t oi = boff + (size_t)(bn + ty + i) * K + bk + tx;
    short hi, lo; split2(v, hi, lo);
    outH[oi] = hi;
    if (SPLIT) outL[oi] = lo;
  }
}

// ---------------- split GEMM: C = (AH+AL)[M,K] @ (BH+BL)[N,K]^T, 3-term emulated f32 -----
// EPI 0: write split pair CH/CL (bf16).  EPI 1: write f32 C = acc + res.
template<int EPI>
__global__ __launch_bounds__(256) void gemm_split_kernel(
    const short* __restrict__ AH, const short* __restrict__ AL,
    const short* __restrict__ BH, const short* __restrict__ BL,
    short* __restrict__ CH, short* __restrict__ CL,
    float* __restrict__ Cf, const float* __restrict__ res,
    int M, int N, int K)
{
  __shared__ __align__(16) short AsH[128*32], AsL[128*32], BsH[128*32], BsL[128*32];
  int bm = blockIdx.x * 128, bn = blockIdx.y * 128;
  int tid = threadIdx.x;
  int wave = tid >> 6, lane = tid & 63;
  int g = lane >> 4, r16 = lane & 15;
  int wr = wave >> 1, wc = wave & 1;
  f32x4 acc[4][4];
  #pragma unroll
  for (int m = 0; m < 4; ++m)
    #pragma unroll
    for (int n = 0; n < 4; ++n) acc[m][n] = (f32x4){0.f,0.f,0.f,0.f};
  int flat0 = tid * 8;
  for (int k0 = 0; k0 < K; k0 += 32) {
    __syncthreads();
    #pragma unroll
    for (int it = 0; it < 2; ++it) {
      int flat = it * 2048 + flat0;
      int row = flat >> 5, col = flat & 31;
      size_t ga = (size_t)(bm + row) * K + k0 + col;
      size_t gb = (size_t)(bn + row) * K + k0 + col;
      int lo = it * 4096 + wave * 1024;
      __builtin_amdgcn_global_load_lds((__attribute__((address_space(1))) void*)(AH + ga),
                                       (__attribute__((address_space(3))) void*)((char*)AsH + lo), 16, 0, 0);
      __builtin_amdgcn_global_load_lds((__attribute__((address_space(1))) void*)(AL + ga),
                                       (__attribute__((address_space(3))) void*)((char*)AsL + lo), 16, 0, 0);
      __builtin_amdgcn_global_load_lds((__attribute__((address_space(1))) void*)(BH + gb),
                                       (__attribute__((address_space(3))) void*)((char*)BsH + lo), 16, 0, 0);
      __builtin_amdgcn_global_load_lds((__attribute__((address_space(1))) void*)(BL + gb),
                                       (__attribute__((address_space(3))) void*)((char*)BsL + lo), 16, 0, 0);
    }
    __syncthreads();
    short8 afh[4], afl[4], bfh[4], bfl[4];
    #pragma unroll
    for (int m = 0; m < 4; ++m) {
      int off = (64*wr + 16*m + r16) * 32 + g * 8;
      afh[m] = *(const short8*)(AsH + off);
      afl[m] = *(const short8*)(AsL + off);
    }
    #pragma unroll
    for (int n = 0; n < 4; ++n) {
      int off = (64*wc + 16*n + r16) * 32 + g * 8;
      bfh[n] = *(const short8*)(BsH + off);
      bfl[n] = *(const short8*)(BsL + off);
    }
    #pragma unroll
    for (int m = 0; m < 4; ++m)
      #pragma unroll
      for (int n = 0; n < 4; ++n) {
        acc[m][n] = __builtin_amdgcn_mfma_f32_16x16x32_bf16(afh[m], bfh[n], acc[m][n], 0, 0, 0);
        acc[m][n] = __builtin_amdgcn_mfma_f32_16x16x32_bf16(afh[m], bfl[n], acc[m][n], 0, 0, 0);
        acc[m][n] = __builtin_amdgcn_mfma_f32_16x16x32_bf16(afl[m], bfh[n], acc[m][n], 0, 0, 0);
      }
  }
  #pragma unroll
  for (int m = 0; m < 4; ++m)
    #pragma unroll
    for (int n = 0; n < 4; ++n)
      #pragma unroll
      for (int r = 0; r < 4; ++r) {
        int row = bm + 64*wr + 16*m + g*4 + r;
        int col = bn + 64*wc + 16*n + r16;
        size_t idx = (size_t)row * N + col;
        float v = acc[m][n][r];
        if (EPI == 0) {
          short hi, lo; split2(v, hi, lo);
          CH[idx] = hi; CL[idx] = lo;
        } else {
          Cf[idx] = v + res[idx];
        }
      }
}

// ---------------- plain bf16 GEMM (MoE path) ---------------------------------------------
// EPI 0: C bf16 store (z-batched).  EPI 2: C f32 += gates[row,eidx]*acc.
template<int EPI>
__global__ __launch_bounds__(256) void gemm_bt_kernel(
    const short* __restrict__ A, const short* __restrict__ Bt, void* __restrict__ Cv,
    const float* __restrict__ gates, int eidx,
    int M, int N, int K, long sBt, long sC)
{
  __shared__ __align__(16) short As[128*32];
  __shared__ __align__(16) short Bs[128*32];
  int z = blockIdx.z;
  const short* Ab = A;
  const short* Bb = Bt + (size_t)z * sBt;
  int bm = blockIdx.x * 128, bn = blockIdx.y * 128;
  int tid = threadIdx.x;
  int wave = tid >> 6, lane = tid & 63;
  int g = lane >> 4, r16 = lane & 15;
  int wr = wave >> 1, wc = wave & 1;
  f32x4 acc[4][4];
  #pragma unroll
  for (int m = 0; m < 4; ++m)
    #pragma unroll
    for (int n = 0; n < 4; ++n) acc[m][n] = (f32x4){0.f,0.f,0.f,0.f};
  int flat0 = tid * 8;
  for (int k0 = 0; k0 < K; k0 += 32) {
    __syncthreads();
    #pragma unroll
    for (int it = 0; it < 2; ++it) {
      int flat = it * 2048 + flat0;
      int row = flat >> 5, col = flat & 31;
      const short* ga = Ab + (size_t)(bm + row) * K + k0 + col;
      const short* gb = Bb + (size_t)(bn + row) * K + k0 + col;
      char* la = (char*)As + it * 4096 + wave * 1024;
      char* lb = (char*)Bs + it * 4096 + wave * 1024;
      __builtin_amdgcn_global_load_lds((__attribute__((address_space(1))) void*)ga,
                                       (__attribute__((address_space(3))) void*)la, 16, 0, 0);
      __builtin_amdgcn_global_load_lds((__attribute__((address_space(1))) void*)gb,
                                       (__attribute__((address_space(3))) void*)lb, 16, 0, 0);
    }
    __syncthreads();
    short8 af[4], bfv[4];
    #pragma unroll
    for (int m = 0; m < 4; ++m)
      af[m] = *(const short8*)(As + (64*wr + 16*m + r16) * 32 + g * 8);
    #pragma unroll
    for (int n = 0; n < 4; ++n)
      bfv[n] = *(const short8*)(Bs + (64*wc + 16*n + r16) * 32 + g * 8);
    #pragma unroll
    for (int m = 0; m < 4; ++m)
      #pragma unroll
      for (int n = 0; n < 4; ++n)
        acc[m][n] = __builtin_amdgcn_mfma_f32_16x16x32_bf16(af[m], bfv[n], acc[m][n], 0, 0, 0);
  }
  #pragma unroll
  for (int m = 0; m < 4; ++m)
    #pragma unroll
    for (int n = 0; n < 4; ++n)
      #pragma unroll
      for (int r = 0; r < 4; ++r) {
        int row = bm + 64*wr + 16*m + g*4 + r;
        int col = bn + 64*wc + 16*n + r16;
        size_t idx = (size_t)row * N + col;
        float v = acc[m][n][r];
        if (EPI == 0) {
          ((short*)Cv + (size_t)z * sC)[idx] = f2bf(v);
        } else {
          ((float*)Cv)[idx] += gates[(size_t)row * 8 + eidx] * v;
        }
      }
}

// ---------------- RoPE in-place on split q,k (token-major B,S,H,HD) ----------------------
__global__ __launch_bounds__(256) void rope_inplace_kernel(
    short* __restrict__ QH, short* __restrict__ QL,
    short* __restrict__ KH, short* __restrict__ KL,
    const int* __restrict__ pos_ids, const float* __restrict__ invtab)
{
  int token = blockIdx.x, tid = threadIdx.x;
  float pos = (float)pos_ids[token];
  #pragma unroll
  for (int it = 0; it < 2; ++it) {
    int p = it * 256 + tid;              // (head, freq) pairs: 16*32 = 512
    int h = p >> 5, j = p & 31;
    float ang = pos * invtab[j];         // f32 mult, matches numpy
    float sn, cs; sincosf(ang, &sn, &cs);
    size_t i1 = (size_t)token * 1024 + h * 64 + j;
    size_t i2 = i1 + 32;
    float q1 = bf2f(QH[i1]) + bf2f(QL[i1]);
    float q2 = bf2f(QH[i2]) + bf2f(QL[i2]);
    float a = q1 * cs - q2 * sn, bq = q1 * sn + q2 * cs;
    short hi, lo;
    split2(a,  hi, lo); QH[i1] = hi; QL[i1] = lo;
    split2(bq, hi, lo); QH[i2] = hi; QL[i2] = lo;
    float k1 = bf2f(KH[i1]) + bf2f(KL[i1]);
    float k2 = bf2f(KH[i2]) + bf2f(KL[i2]);
    a = k1 * cs - k2 * sn; bq = k1 * sn + k2 * cs;
    split2(a,  hi, lo); KH[i1] = hi; KL[i1] = lo;
    split2(bq, hi, lo); KH[i2] = hi; KL[i2] = lo;
  }
}

// ---------------- causal flash attention, split-precision, 1 wave / 16 q-rows ------------
// Swapped QK^T: S^T = mfma(K, Q^T) (rows=kv, cols=q) -> per-lane-column softmax.
__global__ __launch_bounds__(64) void attn_kernel(
    const short* __restrict__ QH, const short* __restrict__ QL,
    const short* __restrict__ KH, const short* __restrict__ KL,
    const short* __restrict__ VH, const short* __restrict__ VL,
    short* __restrict__ OH, short* __restrict__ OL)
{
  __shared__ __align__(16) char kldsH[4096], kldsL[4096], vldsH[4096], vldsL[4096];
  int qb = blockIdx.x * 16;
  int bh = blockIdx.y;
  int b = bh >> 4, h = bh & 15;
  int lane = threadIdx.x;
  int g = lane >> 4, r16 = lane & 15;
  // token-major elem index for (s, d) of this (b, h)
  auto gidx = [&](int s, int d) -> size_t {
    return ((size_t)(b * 2048 + s) * 16 + h) * 64 + d;
  };
  short8 qf0h = *(const short8*)(QH + gidx(qb + r16, g * 8));
  short8 qf0l = *(const short8*)(QL + gidx(qb + r16, g * 8));
  short8 qf1h = *(const short8*)(QH + gidx(qb + r16, 32 + g * 8));
  short8 qf1l = *(const short8*)(QL + gidx(qb + r16, 32 + g * 8));
  f32x4 o[4];
  #pragma unroll
  for (int c = 0; c < 4; ++c) o[c] = (f32x4){0.f,0.f,0.f,0.f};
  float mrun = -1e30f, lsum = 0.f;
  int qi = qb + r16;
  int nkb = (qb + 47) >> 5;
  for (int kb = 0; kb < nkb; ++kb) {
    int kvb = kb * 32;
    #pragma unroll
    for (int i = 0; i < 4; ++i) {       // stage K,V hi/lo: 32x64 bf16 each, XOR swizzle
      int flat = i * 64 + lane;
      int row = flat >> 3, c16 = flat & 7;
      int bo = row * 128 + ((c16 * 16) ^ ((row & 7) << 4));
      size_t gs = gidx(kvb + row, c16 * 8);
      *(short8*)(kldsH + bo) = *(const short8*)(KH + gs);
      *(short8*)(kldsL + bo) = *(const short8*)(KL + gs);
      *(short8*)(vldsH + bo) = *(const short8*)(VH + gs);
      *(short8*)(vldsL + bo) = *(const short8*)(VL + gs);
    }
    __syncthreads();
    f32x4 st[2];
    #pragma unroll
    for (int T = 0; T < 2; ++T) {
      int krow = 16 * T + r16;
      int o0 = krow * 128 + ((g * 16) ^ ((r16 & 7) << 4));
      int o1 = krow * 128 + ((64 + g * 16) ^ ((r16 & 7) << 4));
      short8 k0h = *(const short8*)(kldsH + o0);
      short8 k0l = *(const short8*)(kldsL + o0);
      short8 k1h = *(const short8*)(kldsH + o1);
      short8 k1l = *(const short8*)(kldsL + o1);
      f32x4 a = (f32x4){0.f,0.f,0.f,0.f};
      a = __builtin_amdgcn_mfma_f32_16x16x32_bf16(k0h, qf0h, a, 0, 0, 0);
      a = __builtin_amdgcn_mfma_f32_16x16x32_bf16(k0h, qf0l, a, 0, 0, 0);
      a = __builtin_amdgcn_mfma_f32_16x16x32_bf16(k0l, qf0h, a, 0, 0, 0);
      a = __builtin_amdgcn_mfma_f32_16x16x32_bf16(k1h, qf1h, a, 0, 0, 0);
      a = __builtin_amdgcn_mfma_f32_16x16x32_bf16(k1h, qf1l, a, 0, 0, 0);
      a = __builtin_amdgcn_mfma_f32_16x16x32_bf16(k1l, qf1h, a, 0, 0, 0);
      st[T] = a;
    }
    float p8[8]; float tm = -1e30f;
    #pragma unroll
    for (int T = 0; T < 2; ++T)
      #pragma unroll
      for (int r = 0; r < 4; ++r) {
        float sv = st[T][r] * 0.125f;            // 1/sqrt(64)
        int kvi = kvb + 16*T + 4*g + r;
        sv = (kvi > qi) ? -1e30f : sv;           // causal
        p8[T*4 + r] = sv;
        tm = fmaxf(tm, sv);
      }
    tm = fmaxf(tm, __shfl_xor(tm, 16));
    tm = fmaxf(tm, __shfl_xor(tm, 32));
    float mnew = fmaxf(mrun, tm);
    float sf = expf(mrun - mnew);
    float ps = 0.f;
    #pragma unroll
    for (int i = 0; i < 8; ++i) { p8[i] = expf(p8[i] - mnew); ps += p8[i]; }
    ps += __shfl_xor(ps, 16);
    ps += __shfl_xor(ps, 32);
    lsum = lsum * sf + ps;
    mrun = mnew;
    float sfr[4];
    #pragma unroll
    for (int r = 0; r < 4; ++r) sfr[r] = __shfl(sf, 4*g + r);   // sf keyed by q=lane&15
    #pragma unroll
    for (int c = 0; c < 4; ++c)
      #pragma unroll
      for (int r = 0; r < 4; ++r) o[c][r] *= sfr[r];
    // Redistribute P^T -> P A-frag (verified lane mapping), then split hi/lo.
    float pav[8];
    #pragma unroll
    for (int j = 0; j < 8; ++j) {
      int src = ((g & 1) * 2 + (j >> 2)) * 16 + r16;
      float v0 = __shfl(p8[j & 3], src);
      float v1 = __shfl(p8[4 + (j & 3)], src);
      pav[j] = (g >= 2) ? v1 : v0;
    }
    short8 pah, pal;
    #pragma unroll
    for (int j = 0; j < 8; ++j) {
      short hi, lo; split2(pav[j], hi, lo);
      pah[j] = hi; pal[j] = lo;
    }
    #pragma unroll
    for (int c = 0; c < 4; ++c) {          // O[q,d] += P @ V, d-chunk c
      short8 vbh, vbl;
      #pragma unroll
      for (int j = 0; j < 8; ++j) {
        int vrow = 8 * g + j;
        int bo = vrow * 128 + ((32 * c + 2 * r16) ^ ((vrow & 7) << 4));
        vbh[j] = *(const short*)(vldsH + bo);
        vbl[j] = *(const short*)(vldsL + bo);
      }
      o[c] = __builtin_amdgcn_mfma_f32_16x16x32_bf16(pah, vbh, o[c], 0, 0, 0);
      o[c] = __builtin_amdgcn_mfma_f32_16x16x32_bf16(pah, vbl, o[c], 0, 0, 0);
      o[c] = __builtin_amdgcn_mfma_f32_16x16x32_bf16(pal, vbh, o[c], 0, 0, 0);
    }
    __syncthreads();
  }
  float lr[4];
  #pragma unroll
  for (int r = 0; r < 4; ++r) lr[r] = __shfl(lsum, 4*g + r);
  #pragma unroll
  for (int c = 0; c < 4; ++c)
    #pragma unroll
    for (int r = 0; r < 4; ++r) {
      int q = qb + 4*g + r;
      int d = 16*c + r16;
      float v = o[c][r] / lr[r];
      short hi, lo; split2(v, hi, lo);
      size_t oi = gidx(q, d);
      OH[oi] = hi; OL[oi] = lo;
    }
}

// ---------------- router: f32 rmsnorm'd xmid @ wr -> sigmoid -> biased top2 -> gates -----
__global__ __launch_bounds__(256) void router_kernel(
    const float* __restrict__ xmid, const float* __restrict__ invrms,
    const float* __restrict__ w2norm, const float* __restrict__ wr,
    const float* __restrict__ rbias, float* __restrict__ gates)
{
  int row = blockIdx.x, tid = threadIdx.x;
  float invr = invrms[row];
  float part[8] = {0,0,0,0,0,0,0,0};
  for (int d = tid; d < 1024; d += 256) {
    float xv = xmid[(size_t)row * 1024 + d] * invr * w2norm[d];
    #pragma unroll
    for (int e = 0; e < 8; ++e) part[e] += xv * wr[d * 8 + e];
  }
  #pragma unroll
  for (int e = 0; e < 8; ++e)
    #pragma unroll
    for (int off = 32; off > 0; off >>= 1) part[e] += __shfl_down(part[e], off);
  __shared__ float red[4][8];
  if ((tid & 63) == 0)
    #pragma unroll
    for (int e = 0; e < 8; ++e) red[tid >> 6][e] = part[e];
  __syncthreads();
  if (tid == 0) {
    float sc[8], bs[8];
    #pragma unroll
    for (int e = 0; e < 8; ++e) {
      float t = red[0][e] + red[1][e] + red[2][e] + red[3][e];
      sc[e] = 1.f / (1.f + expf(-t));
      bs[e] = sc[e] + rbias[e];
    }
    int i0 = 0;
    #pragma unroll
    for (int e = 1; e < 8; ++e) if (bs[e] > bs[i0]) i0 = e;   // ties -> lowest idx
    int i1 = -1;
    #pragma unroll
    for (int e = 0; e < 8; ++e) if (e != i0 && (i1 < 0 || bs[e] > bs[i1])) i1 = e;
    float s0 = sc[i0], s1 = sc[i1];
    float den = s0 + s1 + 1e-9f;
    #pragma unroll
    for (int e = 0; e < 8; ++e)
      gates[(size_t)row * 8 + e] = (e == i0) ? s0 / den : ((e == i1) ? s1 / den : 0.f);
  }
}

// ---------------- silu(h1)*h3 elementwise, bf16 (in-place safe) --------------------------
__global__ __launch_bounds__(256) void silu_mul_kernel(
    const short* __restrict__ h1, const short* __restrict__ h3, short* __restrict__ h)
{
  size_t i = ((size_t)blockIdx.x * 256 + threadIdx.x) * 8;
  short8 a = *(const short8*)(h1 + i);
  short8 b3 = *(const short8*)(h3 + i);
  short8 r;
  #pragma unroll
  for (int j = 0; j < 8; ++j) {
    float x = bf2f(a[j]);
    float y = bf2f(b3[j]);
    r[j] = f2bf((x / (1.f + expf(-x))) * y);
  }
  *(short8*)(h + i) = r;
}

// ---------------- workspace layout (1 MB = 1048576 B) ------------------------------------
#define MB (1048576ull)
enum : unsigned long long {
  OFF_WQTH  = 0*MB,  OFF_WQTL  = 2*MB,          // 1024x1024 bf16, 2MB each
  OFF_WDKVH = 4*MB,  OFF_WDKVL = 4*MB + 512*1024,   // 256x1024
  OFF_WUKH  = 5*MB,  OFF_WUKL  = 5*MB + 512*1024,   // 1024x256
  OFF_WUVH  = 6*MB,  OFF_WUVL  = 6*MB + 512*1024,
  OFF_WOTH  = 7*MB,  OFF_WOTL  = 9*MB,
  OFF_W1T   = 11*MB, OFF_W3T   = 15*MB, OFF_W2T = 19*MB,  // plain bf16, 4MB each
  OFF_X1H   = 23*MB, OFF_X1L   = 31*MB,          // 4096x1024 bf16, 8MB each
  OFF_QTH   = 39*MB, OFF_QTL   = 47*MB,
  OFF_CH    = 55*MB, OFF_CL    = 57*MB,          // 4096x256, 2MB each
  OFF_KTH   = 59*MB, OFF_KTL   = 67*MB,
  OFF_VTH   = 75*MB, OFF_VTL   = 83*MB,
  // aliases (time-disjoint):
  OFF_AOH   = 23*MB, OFF_AOL   = 31*MB,          // attn out (X1 dead)
  OFF_XMID  = 39*MB,                             // f32 16MB (QT dead)
  OFF_X2    = 55*MB,                             // bf16 8MB (C + KTH head dead)
  OFF_H1    = 23*MB,                             // 16MB (AO dead after wo) ; HALL in-place
  OFF_H3    = 39*MB,                             // 16MB (XMID dead after router)
  OFF_INVT  = 91*MB,
  OFF_INVR  = 91*MB + 4096,
  OFF_GATES = 91*MB + 32768,
  WS_NEEDED = 91*MB + 262144
};

extern "C" void kernel_launch(void* const* d_in, const int* in_sizes, int n_in,
                              void* d_out, int out_size, void* d_ws, size_t ws_size,
                              hipStream_t stream) {
  const float* x     = (const float*)d_in[0];
  const int*   pos   = (const int*)d_in[1];
  const float* n1w   = (const float*)d_in[2];
  const float* wq    = (const float*)d_in[3];
  const float* wdkv  = (const float*)d_in[4];
  const float* wuk   = (const float*)d_in[5];
  const float* wuv   = (const float*)d_in[6];
  const float* wo    = (const float*)d_in[7];
  const float* n2w   = (const float*)d_in[8];
  const float* wr    = (const float*)d_in[9];
  const float* rbias = (const float*)d_in[10];
  const float* w1    = (const float*)d_in[11];
  const float* w3    = (const float*)d_in[12];
  const float* w2    = (const float*)d_in[13];
  float* out = (float*)d_out;
  char* ws = (char*)d_ws;
  if (ws_size < WS_NEEDED) return;  // loud failure if scratch too small

  short *WQTH=(short*)(ws+OFF_WQTH), *WQTL=(short*)(ws+OFF_WQTL);
  short *WDKVH=(short*)(ws+OFF_WDKVH), *WDKVL=(short*)(ws+OFF_WDKVL);
  short *WUKH=(short*)(ws+OFF_WUKH), *WUKL=(short*)(ws+OFF_WUKL);
  short *WUVH=(short*)(ws+OFF_WUVH), *WUVL=(short*)(ws+OFF_WUVL);
  short *WOTH=(short*)(ws+OFF_WOTH), *WOTL=(short*)(ws+OFF_WOTL);
  short *W1T=(short*)(ws+OFF_W1T), *W3T=(short*)(ws+OFF_W3T), *W2T=(short*)(ws+OFF_W2T);
  short *X1H=(short*)(ws+OFF_X1H), *X1L=(short*)(ws+OFF_X1L);
  short *QTH=(short*)(ws+OFF_QTH), *QTL=(short*)(ws+OFF_QTL);
  short *CH=(short*)(ws+OFF_CH),   *CL=(short*)(ws+OFF_CL);
  short *KTH=(short*)(ws+OFF_KTH), *KTL=(short*)(ws+OFF_KTL);
  short *VTH=(short*)(ws+OFF_VTH), *VTL=(short*)(ws+OFF_VTL);
  short *AOH=(short*)(ws+OFF_AOH), *AOL=(short*)(ws+OFF_AOL);
  float *XMID=(float*)(ws+OFF_XMID);
  short *X2=(short*)(ws+OFF_X2);
  short *H1=(short*)(ws+OFF_H1), *H3=(short*)(ws+OFF_H3);
  float *INVT=(float*)(ws+OFF_INVT), *INVR=(float*)(ws+OFF_INVR), *GATES=(float*)(ws+OFF_GATES);

  // 0) rope inv-freq table (bit-faithful to numpy)
  invtab_kernel<<<1, 64, 0, stream>>>(INVT);
  // 1) x1 = rmsnorm(x) -> split
  rmsnorm_kernel<<<4096, 256, 0, stream>>>(x, n1w, X1H, X1L, nullptr, nullptr);
  // 2) weight transpose+convert (split for attn path, plain for MoE)
  transpose_conv_kernel<true ><<<dim3(32,32,1), 256, 0, stream>>>(wq,   WQTH, WQTL, 1024, 1024);
  transpose_conv_kernel<true ><<<dim3( 8,32,1), 256, 0, stream>>>(wdkv, WDKVH, WDKVL, 1024, 256);
  transpose_conv_kernel<true ><<<dim3(32, 8,1), 256, 0, stream>>>(wuk,  WUKH, WUKL, 256, 1024);
  transpose_conv_kernel<true ><<<dim3(32, 8,1), 256, 0, stream>>>(wuv,  WUVH, WUVL, 256, 1024);
  transpose_conv_kernel<true ><<<dim3(32,32,1), 256, 0, stream>>>(wo,   WOTH, WOTL, 1024, 1024);
  transpose_conv_kernel<false><<<dim3( 8,32,8), 256, 0, stream>>>(w1,   W1T, nullptr, 1024, 256);
  transpose_conv_kernel<false><<<dim3( 8,32,8), 256, 0, stream>>>(w3,   W3T, nullptr, 1024, 256);
  transpose_conv_kernel<false><<<dim3(32, 8,8), 256, 0, stream>>>(w2,   W2T, nullptr, 256, 1024);
  // 3) q = x1@wq ; c = x1@wdkv ; k = c@wuk ; v = c@wuv   (split, token-major)
  gemm_split_kernel<0><<<dim3(32,8), 256, 0, stream>>>(X1H, X1L, WQTH, WQTL, QTH, QTL, nullptr, nullptr, 4096, 1024, 1024);
  gemm_split_kernel<0><<<dim3(32,2), 256, 0, stream>>>(X1H, X1L, WDKVH, WDKVL, CH, CL, nullptr, nullptr, 4096, 256, 1024);
  gemm_split_kernel<0><<<dim3(32,8), 256, 0, stream>>>(CH, CL, WUKH, WUKL, KTH, KTL, nullptr, nullptr, 4096, 1024, 256);
  gemm_split_kernel<0><<<dim3(32,8), 256, 0, stream>>>(CH, CL, WUVH, WUVL, VTH, VTL, nullptr, nullptr, 4096, 1024, 256);
  // 4) rope in-place on q,k
  rope_inplace_kernel<<<4096, 256, 0, stream>>>(QTH, QTL, KTH, KTL, pos, INVT);
  // 5) causal attention (split) -> AO (token-major)
  attn_kernel<<<dim3(128,32), 64, 0, stream>>>(QTH, QTL, KTH, KTL, VTH, VTL, AOH, AOL);
  // 6) xmid = x + attn@wo  (f32)
  gemm_split_kernel<1><<<dim3(32,8), 256, 0, stream>>>(AOH, AOL, WOTH, WOTL, nullptr, nullptr, XMID, x, 4096, 1024, 1024);
  // 7) x2 = rmsnorm(xmid) (plain bf16) + invrms; copy xmid into d_out
  rmsnorm_kernel<<<4096, 256, 0, stream>>>(XMID, n2w, X2, nullptr, INVR, out);
  // 8) router gates (exact f32 path)
  router_kernel<<<4096, 256, 0, stream>>>(XMID, INVR, n2w, wr, rbias, GATES);
  // 9) dense MoE: h1/h3 batched over experts, silu*mul (in-place), per-expert w2 accumulate
  gemm_bt_kernel<0><<<dim3(32,2,8), 256, 0, stream>>>(X2, W1T, H1, nullptr, 0, 4096, 256, 1024, 262144, 1048576);
  gemm_bt_kernel<0><<<dim3(32,2,8), 256, 0, stream>>>(X2, W3T, H3, nullptr, 0, 4096, 256, 1024, 262144, 1048576);
  silu_mul_kernel<<<4096, 256, 0, stream>>>(H1, H3, H1);
  for (int e = 0; e < 8; ++e)
    gemm_bt_kernel<2><<<dim3(32,8,1), 256, 0, stream>>>(H1 + (size_t)e * 1048576,
                                                        W2T + (size_t)e * 262144,
                                                        out, GATES, e,
                                                        4096, 1024, 256, 0, 0);
}

// Round 4
// 697.506 us; speedup vs baseline: 1.7226x; 1.7226x over previous
//
#include <hip/hip_runtime.h>
#include <hip/hip_bf16.h>
#include <math.h>

// DeepSeekV3-style block: rmsnorm -> MLA attn -> residual -> rmsnorm -> MoE -> residual
// B=2 S=2048 D=1024 H=16 HD=64 R=256 E=8 K=2 MH=256
//
// Precision: attention path (x1 -> q,c,k,v -> attn -> @wo -> xmid) in emulated fp32
// (bf16 hi/lo pairs, 3-term MFMA) so router top-2 doesn't flip. MoE path plain bf16.

typedef __attribute__((ext_vector_type(8))) short short8;
typedef __attribute__((ext_vector_type(4))) float f32x4;

static __device__ __forceinline__ float bf2f(short s) {
  union { unsigned u; float f; } c; c.u = ((unsigned)(unsigned short)s) << 16; return c.f;
}
static __device__ __forceinline__ short f2bf(float f) {
  __hip_bfloat16 h = __float2bfloat16(f);
  short s; __builtin_memcpy(&s, &h, sizeof(s)); return s;
}
static __device__ __forceinline__ void split2(float v, short& hi, short& lo) {
  hi = f2bf(v); lo = f2bf(v - bf2f(hi));
}

// ---------------- RoPE inv-freq table, bit-faithful to numpy f32 -------------------------
__global__ void invtab_kernel(float* __restrict__ tab) {
  int j = threadIdx.x;
  if (j < 32) {
    float t = (float)pow(10000.0, (double)j * (1.0 / 32.0));
    tab[j] = 1.0f / t;
  }
}

// ---------------- rmsnorm: f32 in -> bf16 hi (+optional lo, invrms, f32 copy) ------------
__global__ __launch_bounds__(256) void rmsnorm_kernel(
    const float* __restrict__ in, const float* __restrict__ w,
    short* __restrict__ outH, short* __restrict__ outL,
    float* __restrict__ invrms, float* __restrict__ cpy)
{
  int row = blockIdx.x, tid = threadIdx.x;
  const float4* xv = (const float4*)(in + (size_t)row * 1024);
  float4 v = xv[tid];
  float ss = v.x*v.x + v.y*v.y + v.z*v.z + v.w*v.w;
  #pragma unroll
  for (int off = 32; off > 0; off >>= 1) ss += __shfl_down(ss, off);
  __shared__ float wsum[4];
  if ((tid & 63) == 0) wsum[tid >> 6] = ss;
  __syncthreads();
  float inv = rsqrtf((wsum[0] + wsum[1] + wsum[2] + wsum[3]) * (1.0f/1024.0f) + 1e-6f);
  float4 wv = ((const float4*)w)[tid];
  size_t base = (size_t)row * 1024 + (size_t)tid * 4;
  float r[4] = { v.x*inv*wv.x, v.y*inv*wv.y, v.z*inv*wv.z, v.w*inv*wv.w };
  #pragma unroll
  for (int j = 0; j < 4; ++j) {
    short hi, lo; split2(r[j], hi, lo);
    outH[base + j] = hi;
    if (outL) outL[base + j] = lo;
  }
  if (cpy) ((float4*)cpy)[(size_t)row * 256 + tid] = v;
  if (invrms && tid == 0) invrms[row] = inv;
}

// ---------------- transpose+convert: f32 (K,N) -> bf16 (N,K) hi(/lo), batched z ----------
template<bool SPLIT>
__global__ __launch_bounds__(256) void transpose_conv_kernel(
    const float* __restrict__ in, short* __restrict__ outH, short* __restrict__ outL,
    int K, int N)
{
  __shared__ float tile[32][33];
  size_t boff = (size_t)blockIdx.z * K * N;
  const float* ip = in + boff;
  int bn = blockIdx.x * 32, bk = blockIdx.y * 32;
  int tx = threadIdx.x & 31, ty = threadIdx.x >> 5;
  #pragma unroll
  for (int i = 0; i < 32; i += 8)
    tile[ty + i][tx] = ip[(size_t)(bk + ty + i) * N + bn + tx];
  __syncthreads();
  #pragma unroll
  for (int i = 0; i < 32; i += 8) {
    float v = tile[tx][ty + i];
    size_t oi = boff + (size_t)(bn + ty + i) * K + bk + tx;
    short hi, lo; split2(v, hi, lo);
    outH[oi] = hi;
    if (SPLIT) outL[oi] = lo;
  }
}

// ---------------- split GEMM: C = (AH+AL)[M,K] @ (BH+BL)[N,K]^T, 3-term emulated f32 -----
template<int EPI>
__global__ __launch_bounds__(256) void gemm_split_kernel(
    const short* __restrict__ AH, const short* __restrict__ AL,
    const short* __restrict__ BH, const short* __restrict__ BL,
    short* __restrict__ CH, short* __restrict__ CL,
    float* __restrict__ Cf, const float* __restrict__ res,
    int M, int N, int K)
{
  __shared__ __align__(16) short AsH[128*32], AsL[128*32], BsH[128*32], BsL[128*32];
  int bm = blockIdx.x * 128, bn = blockIdx.y * 128;
  int tid = threadIdx.x;
  int wave = tid >> 6, lane = tid & 63;
  int g = lane >> 4, r16 = lane & 15;
  int wr = wave >> 1, wc = wave & 1;
  f32x4 acc[4][4];
  #pragma unroll
  for (int m = 0; m < 4; ++m)
    #pragma unroll
    for (int n = 0; n < 4; ++n) acc[m][n] = (f32x4){0.f,0.f,0.f,0.f};
  int flat0 = tid * 8;
  for (int k0 = 0; k0 < K; k0 += 32) {
    __syncthreads();
    #pragma unroll
    for (int it = 0; it < 2; ++it) {
      int flat = it * 2048 + flat0;
      int row = flat >> 5, col = flat & 31;
      size_t ga = (size_t)(bm + row) * K + k0 + col;
      size_t gb = (size_t)(bn + row) * K + k0 + col;
      int lo = it * 4096 + wave * 1024;
      __builtin_amdgcn_global_load_lds((__attribute__((address_space(1))) void*)(AH + ga),
                                       (__attribute__((address_space(3))) void*)((char*)AsH + lo), 16, 0, 0);
      __builtin_amdgcn_global_load_lds((__attribute__((address_space(1))) void*)(AL + ga),
                                       (__attribute__((address_space(3))) void*)((char*)AsL + lo), 16, 0, 0);
      __builtin_amdgcn_global_load_lds((__attribute__((address_space(1))) void*)(BH + gb),
                                       (__attribute__((address_space(3))) void*)((char*)BsH + lo), 16, 0, 0);
      __builtin_amdgcn_global_load_lds((__attribute__((address_space(1))) void*)(BL + gb),
                                       (__attribute__((address_space(3))) void*)((char*)BsL + lo), 16, 0, 0);
    }
    __syncthreads();
    short8 afh[4], afl[4], bfh[4], bfl[4];
    #pragma unroll
    for (int m = 0; m < 4; ++m) {
      int off = (64*wr + 16*m + r16) * 32 + g * 8;
      afh[m] = *(const short8*)(AsH + off);
      afl[m] = *(const short8*)(AsL + off);
    }
    #pragma unroll
    for (int n = 0; n < 4; ++n) {
      int off = (64*wc + 16*n + r16) * 32 + g * 8;
      bfh[n] = *(const short8*)(BsH + off);
      bfl[n] = *(const short8*)(BsL + off);
    }
    #pragma unroll
    for (int m = 0; m < 4; ++m)
      #pragma unroll
      for (int n = 0; n < 4; ++n) {
        acc[m][n] = __builtin_amdgcn_mfma_f32_16x16x32_bf16(afh[m], bfh[n], acc[m][n], 0, 0, 0);
        acc[m][n] = __builtin_amdgcn_mfma_f32_16x16x32_bf16(afh[m], bfl[n], acc[m][n], 0, 0, 0);
        acc[m][n] = __builtin_amdgcn_mfma_f32_16x16x32_bf16(afl[m], bfh[n], acc[m][n], 0, 0, 0);
      }
  }
  #pragma unroll
  for (int m = 0; m < 4; ++m)
    #pragma unroll
    for (int n = 0; n < 4; ++n)
      #pragma unroll
      for (int r = 0; r < 4; ++r) {
        int row = bm + 64*wr + 16*m + g*4 + r;
        int col = bn + 64*wc + 16*n + r16;
        size_t idx = (size_t)row * N + col;
        float v = acc[m][n][r];
        if (EPI == 0) {
          short hi, lo; split2(v, hi, lo);
          CH[idx] = hi; CL[idx] = lo;
        } else {
          Cf[idx] = v + res[idx];
        }
      }
}

// ---------------- plain bf16 GEMM (MoE path) ---------------------------------------------
template<int EPI>
__global__ __launch_bounds__(256) void gemm_bt_kernel(
    const short* __restrict__ A, const short* __restrict__ Bt, void* __restrict__ Cv,
    const float* __restrict__ gates, int eidx,
    int M, int N, int K, long sBt, long sC)
{
  __shared__ __align__(16) short As[128*32];
  __shared__ __align__(16) short Bs[128*32];
  int z = blockIdx.z;
  const short* Ab = A;
  const short* Bb = Bt + (size_t)z * sBt;
  int bm = blockIdx.x * 128, bn = blockIdx.y * 128;
  int tid = threadIdx.x;
  int wave = tid >> 6, lane = tid & 63;
  int g = lane >> 4, r16 = lane & 15;
  int wr = wave >> 1, wc = wave & 1;
  f32x4 acc[4][4];
  #pragma unroll
  for (int m = 0; m < 4; ++m)
    #pragma unroll
    for (int n = 0; n < 4; ++n) acc[m][n] = (f32x4){0.f,0.f,0.f,0.f};
  int flat0 = tid * 8;
  for (int k0 = 0; k0 < K; k0 += 32) {
    __syncthreads();
    #pragma unroll
    for (int it = 0; it < 2; ++it) {
      int flat = it * 2048 + flat0;
      int row = flat >> 5, col = flat & 31;
      const short* ga = Ab + (size_t)(bm + row) * K + k0 + col;
      const short* gb = Bb + (size_t)(bn + row) * K + k0 + col;
      char* la = (char*)As + it * 4096 + wave * 1024;
      char* lb = (char*)Bs + it * 4096 + wave * 1024;
      __builtin_amdgcn_global_load_lds((__attribute__((address_space(1))) void*)ga,
                                       (__attribute__((address_space(3))) void*)la, 16, 0, 0);
      __builtin_amdgcn_global_load_lds((__attribute__((address_space(1))) void*)gb,
                                       (__attribute__((address_space(3))) void*)lb, 16, 0, 0);
    }
    __syncthreads();
    short8 af[4], bfv[4];
    #pragma unroll
    for (int m = 0; m < 4; ++m)
      af[m] = *(const short8*)(As + (64*wr + 16*m + r16) * 32 + g * 8);
    #pragma unroll
    for (int n = 0; n < 4; ++n)
      bfv[n] = *(const short8*)(Bs + (64*wc + 16*n + r16) * 32 + g * 8);
    #pragma unroll
    for (int m = 0; m < 4; ++m)
      #pragma unroll
      for (int n = 0; n < 4; ++n)
        acc[m][n] = __builtin_amdgcn_mfma_f32_16x16x32_bf16(af[m], bfv[n], acc[m][n], 0, 0, 0);
  }
  #pragma unroll
  for (int m = 0; m < 4; ++m)
    #pragma unroll
    for (int n = 0; n < 4; ++n)
      #pragma unroll
      for (int r = 0; r < 4; ++r) {
        int row = bm + 64*wr + 16*m + g*4 + r;
        int col = bn + 64*wc + 16*n + r16;
        size_t idx = (size_t)row * N + col;
        float v = acc[m][n][r];
        if (EPI == 0) {
          ((short*)Cv + (size_t)z * sC)[idx] = f2bf(v);
        } else {
          ((float*)Cv)[idx] += gates[(size_t)row * 8 + eidx] * v;
        }
      }
}

// ---------------- RoPE in-place on split q,k (token-major B,S,H,HD) ----------------------
__global__ __launch_bounds__(256) void rope_inplace_kernel(
    short* __restrict__ QH, short* __restrict__ QL,
    short* __restrict__ KH, short* __restrict__ KL,
    const int* __restrict__ pos_ids, const float* __restrict__ invtab)
{
  int token = blockIdx.x, tid = threadIdx.x;
  float pos = (float)pos_ids[token];
  #pragma unroll
  for (int it = 0; it < 2; ++it) {
    int p = it * 256 + tid;
    int h = p >> 5, j = p & 31;
    float ang = pos * invtab[j];
    float sn, cs; sincosf(ang, &sn, &cs);
    size_t i1 = (size_t)token * 1024 + h * 64 + j;
    size_t i2 = i1 + 32;
    float q1 = bf2f(QH[i1]) + bf2f(QL[i1]);
    float q2 = bf2f(QH[i2]) + bf2f(QL[i2]);
    float a = q1 * cs - q2 * sn, bq = q1 * sn + q2 * cs;
    short hi, lo;
    split2(a,  hi, lo); QH[i1] = hi; QL[i1] = lo;
    split2(bq, hi, lo); QH[i2] = hi; QL[i2] = lo;
    float k1 = bf2f(KH[i1]) + bf2f(KL[i1]);
    float k2 = bf2f(KH[i2]) + bf2f(KL[i2]);
    a = k1 * cs - k2 * sn; bq = k1 * sn + k2 * cs;
    split2(a,  hi, lo); KH[i1] = hi; KL[i1] = lo;
    split2(bq, hi, lo); KH[i2] = hi; KL[i2] = lo;
  }
}

// ---------------- V transpose: token-major (b,s,h,d) -> VT[bh][d=64][s=2048] -------------
__global__ __launch_bounds__(256) void v_tr_kernel(
    const short* __restrict__ VH, const short* __restrict__ VL,
    short* __restrict__ TH, short* __restrict__ TL)
{
  __shared__ short th[64][80], tl[64][80];
  int s0 = blockIdx.x * 64, bh = blockIdx.y;
  int b = bh >> 4, h = bh & 15;
  int tid = threadIdx.x;
  #pragma unroll
  for (int p = 0; p < 2; ++p) {
    int flat = p * 256 + tid;
    int sr = flat >> 3, ck = flat & 7;
    size_t gi = ((size_t)((b * 2048) + s0 + sr) * 16 + h) * 64 + ck * 8;
    short8 vh = *(const short8*)(VH + gi);
    short8 vl = *(const short8*)(VL + gi);
    #pragma unroll
    for (int i = 0; i < 8; ++i) { th[sr][ck*8+i] = vh[i]; tl[sr][ck*8+i] = vl[i]; }
  }
  __syncthreads();
  #pragma unroll
  for (int p = 0; p < 2; ++p) {
    int flat = p * 256 + tid;
    int dr = flat >> 3, sc = flat & 7;
    short8 rh, rl;
    #pragma unroll
    for (int i = 0; i < 8; ++i) { rh[i] = th[sc*8+i][dr]; rl[i] = tl[sc*8+i][dr]; }
    size_t go = ((size_t)bh * 64 + dr) * 2048 + s0 + sc * 8;
    *(short8*)(TH + go) = rh;
    *(short8*)(TL + go) = rl;
  }
}

// ---------------- causal flash attention, split precision --------------------------------
// 4 waves/block, 64-row q-tile (16 rows/wave), KVBLK=64, K row-major + V^T in LDS.
// Swapped QK^T: S^T = mfma(K, Q) (rows=kv, cols=q); per-lane-column softmax.
__global__ __launch_bounds__(256) void attn_kernel(
    const short* __restrict__ QH, const short* __restrict__ QL,
    const short* __restrict__ KH, const short* __restrict__ KL,
    const short* __restrict__ VTH, const short* __restrict__ VTL,
    short* __restrict__ OH, short* __restrict__ OL)
{
  __shared__ __align__(16) char ksH[8192], ksL[8192], vtH[8192], vtL[8192];
  int qt = gridDim.x - 1 - blockIdx.x;       // LPT: longest blocks first
  int qb = qt * 64;
  int bh = blockIdx.y;
  int b = bh >> 4, h = bh & 15;
  int tid = threadIdx.x;
  int w = tid >> 6, lane = tid & 63;
  int g = lane >> 4, r16 = lane & 15;
  auto gidx = [&](int s, int d) -> size_t {
    return ((size_t)(b * 2048 + s) * 16 + h) * 64 + d;
  };
  int qrow = qb + 16 * w + r16;
  short8 qf0h = *(const short8*)(QH + gidx(qrow, g * 8));
  short8 qf0l = *(const short8*)(QL + gidx(qrow, g * 8));
  short8 qf1h = *(const short8*)(QH + gidx(qrow, 32 + g * 8));
  short8 qf1l = *(const short8*)(QL + gidx(qrow, 32 + g * 8));
  f32x4 o[4];
  #pragma unroll
  for (int c = 0; c < 4; ++c) o[c] = (f32x4){0.f,0.f,0.f,0.f};
  float mrun = -1e30f, lsum = 0.f;
  int qi = qrow;
  int nt = qt + 1;
  for (int t = 0; t < nt; ++t) {
    int kvb = t * 64;
    __syncthreads();                          // prior tile's LDS reads done
    #pragma unroll
    for (int i = 0; i < 2; ++i) {             // stage K hi/lo (row=kv) + VT hi/lo (row=d)
      int wi = w * 2 + i;
      int row = wi * 8 + (lane >> 3);
      int cs = (lane & 7) ^ (row & 7);        // inverse-swizzled source chunk
      size_t gk = gidx(kvb + row, cs * 8);
      size_t gv = ((size_t)bh * 64 + row) * 2048 + kvb + cs * 8;
      int lb = wi * 1024;
      __builtin_amdgcn_global_load_lds((__attribute__((address_space(1))) void*)(KH + gk),
                                       (__attribute__((address_space(3))) void*)(ksH + lb), 16, 0, 0);
      __builtin_amdgcn_global_load_lds((__attribute__((address_space(1))) void*)(KL + gk),
                                       (__attribute__((address_space(3))) void*)(ksL + lb), 16, 0, 0);
      __builtin_amdgcn_global_load_lds((__attribute__((address_space(1))) void*)(VTH + gv),
                                       (__attribute__((address_space(3))) void*)(vtH + lb), 16, 0, 0);
      __builtin_amdgcn_global_load_lds((__attribute__((address_space(1))) void*)(VTL + gv),
                                       (__attribute__((address_space(3))) void*)(vtL + lb), 16, 0, 0);
    }
    __syncthreads();                          // vmcnt drained by barrier
    float p16[16]; float tm = -1e30f;
    #pragma unroll
    for (int T = 0; T < 4; ++T) {             // S^T tile 16kv x 16q, K=64 split
      int krow = 16 * T + r16;
      int swz = (r16 & 7) << 4;
      short8 k0h = *(const short8*)(ksH + krow * 128 + ((16 * g) ^ swz));
      short8 k0l = *(const short8*)(ksL + krow * 128 + ((16 * g) ^ swz));
      short8 k1h = *(const short8*)(ksH + krow * 128 + ((64 + 16 * g) ^ swz));
      short8 k1l = *(const short8*)(ksL + krow * 128 + ((64 + 16 * g) ^ swz));
      f32x4 a = (f32x4){0.f,0.f,0.f,0.f};
      a = __builtin_amdgcn_mfma_f32_16x16x32_bf16(k0h, qf0h, a, 0, 0, 0);
      a = __builtin_amdgcn_mfma_f32_16x16x32_bf16(k0h, qf0l, a, 0, 0, 0);
      a = __builtin_amdgcn_mfma_f32_16x16x32_bf16(k0l, qf0h, a, 0, 0, 0);
      a = __builtin_amdgcn_mfma_f32_16x16x32_bf16(k1h, qf1h, a, 0, 0, 0);
      a = __builtin_amdgcn_mfma_f32_16x16x32_bf16(k1h, qf1l, a, 0, 0, 0);
      a = __builtin_amdgcn_mfma_f32_16x16x32_bf16(k1l, qf1h, a, 0, 0, 0);
      #pragma unroll
      for (int r = 0; r < 4; ++r) {
        float sv = a[r] * 0.125f;             // 1/sqrt(64)
        int kvi = kvb + 16 * T + 4 * g + r;
        sv = (kvi > qi) ? -1e30f : sv;        // causal
        p16[T * 4 + r] = sv;
        tm = fmaxf(tm, sv);
      }
    }
    tm = fmaxf(tm, __shfl_xor(tm, 16));
    tm = fmaxf(tm, __shfl_xor(tm, 32));
    float mnew = fmaxf(mrun, tm);
    float sf = __expf(mrun - mnew);
    float ps = 0.f;
    #pragma unroll
    for (int i2 = 0; i2 < 16; ++i2) { p16[i2] = __expf(p16[i2] - mnew); ps += p16[i2]; }
    ps += __shfl_xor(ps, 16);
    ps += __shfl_xor(ps, 32);
    lsum = lsum * sf + ps;
    mrun = mnew;
    float sfr[4];
    #pragma unroll
    for (int r = 0; r < 4; ++r) sfr[r] = __shfl(sf, 4 * g + r);
    #pragma unroll
    for (int c = 0; c < 4; ++c)
      #pragma unroll
      for (int r = 0; r < 4; ++r) o[c][r] *= sfr[r];
    // P^T -> P A-frags (kv halves), split hi/lo
    short8 pah[2], pal[2];
    #pragma unroll
    for (int h2 = 0; h2 < 2; ++h2) {
      #pragma unroll
      for (int j = 0; j < 8; ++j) {
        int src = (((2 * g + (j >> 2)) & 3) << 4) + r16;
        float v0 = __shfl(p16[(2 * h2) * 4 + (j & 3)], src);
        float v1 = __shfl(p16[(2 * h2 + 1) * 4 + (j & 3)], src);
        float pv = (g >= 2) ? v1 : v0;
        short phi, plo; split2(pv, phi, plo);
        pah[h2][j] = phi; pal[h2][j] = plo;
      }
    }
    #pragma unroll
    for (int c = 0; c < 4; ++c) {             // O[q,d] += P @ V via VT b128 reads
      #pragma unroll
      for (int h2 = 0; h2 < 2; ++h2) {
        int bo = (16 * c + r16) * 128 + ((64 * h2 + 16 * g) ^ ((r16 & 7) << 4));
        short8 vbh = *(const short8*)(vtH + bo);
        short8 vbl = *(const short8*)(vtL + bo);
        o[c] = __builtin_amdgcn_mfma_f32_16x16x32_bf16(pah[h2], vbh, o[c], 0, 0, 0);
        o[c] = __builtin_amdgcn_mfma_f32_16x16x32_bf16(pah[h2], vbl, o[c], 0, 0, 0);
        o[c] = __builtin_amdgcn_mfma_f32_16x16x32_bf16(pal[h2], vbh, o[c], 0, 0, 0);
      }
    }
  }
  float lr[4];
  #pragma unroll
  for (int r = 0; r < 4; ++r) lr[r] = __shfl(lsum, 4 * g + r);
  #pragma unroll
  for (int c = 0; c < 4; ++c)
    #pragma unroll
    for (int r = 0; r < 4; ++r) {
      int q = qb + 16 * w + 4 * g + r;
      int d = 16 * c + r16;
      float v = o[c][r] / lr[r];
      short hi, lo; split2(v, hi, lo);
      size_t oi = gidx(q, d);
      OH[oi] = hi; OL[oi] = lo;
    }
}

// ---------------- router: f32 rmsnorm'd xmid @ wr -> sigmoid -> biased top2 -> gates -----
__global__ __launch_bounds__(256) void router_kernel(
    const float* __restrict__ xmid, const float* __restrict__ invrms,
    const float* __restrict__ w2norm, const float* __restrict__ wr,
    const float* __restrict__ rbias, float* __restrict__ gates)
{
  int row = blockIdx.x, tid = threadIdx.x;
  float invr = invrms[row];
  float part[8] = {0,0,0,0,0,0,0,0};
  for (int d = tid; d < 1024; d += 256) {
    float xv = xmid[(size_t)row * 1024 + d] * invr * w2norm[d];
    #pragma unroll
    for (int e = 0; e < 8; ++e) part[e] += xv * wr[d * 8 + e];
  }
  #pragma unroll
  for (int e = 0; e < 8; ++e)
    #pragma unroll
    for (int off = 32; off > 0; off >>= 1) part[e] += __shfl_down(part[e], off);
  __shared__ float red[4][8];
  if ((tid & 63) == 0)
    #pragma unroll
    for (int e = 0; e < 8; ++e) red[tid >> 6][e] = part[e];
  __syncthreads();
  if (tid == 0) {
    float sc[8], bs[8];
    #pragma unroll
    for (int e = 0; e < 8; ++e) {
      float t = red[0][e] + red[1][e] + red[2][e] + red[3][e];
      sc[e] = 1.f / (1.f + expf(-t));
      bs[e] = sc[e] + rbias[e];
    }
    int i0 = 0;
    #pragma unroll
    for (int e = 1; e < 8; ++e) if (bs[e] > bs[i0]) i0 = e;
    int i1 = -1;
    #pragma unroll
    for (int e = 0; e < 8; ++e) if (e != i0 && (i1 < 0 || bs[e] > bs[i1])) i1 = e;
    float s0 = sc[i0], s1 = sc[i1];
    float den = s0 + s1 + 1e-9f;
    #pragma unroll
    for (int e = 0; e < 8; ++e)
      gates[(size_t)row * 8 + e] = (e == i0) ? s0 / den : ((e == i1) ? s1 / den : 0.f);
  }
}

// ---------------- silu(h1)*h3 elementwise, bf16 (in-place safe) --------------------------
__global__ __launch_bounds__(256) void silu_mul_kernel(
    const short* __restrict__ h1, const short* __restrict__ h3, short* __restrict__ h)
{
  size_t i = ((size_t)blockIdx.x * 256 + threadIdx.x) * 8;
  short8 a = *(const short8*)(h1 + i);
  short8 b3 = *(const short8*)(h3 + i);
  short8 r;
  #pragma unroll
  for (int j = 0; j < 8; ++j) {
    float x = bf2f(a[j]);
    float y = bf2f(b3[j]);
    r[j] = f2bf((x / (1.f + expf(-x))) * y);
  }
  *(short8*)(h + i) = r;
}

// ---------------- workspace layout (1 MB = 1048576 B) ------------------------------------
#define MB (1048576ull)
enum : unsigned long long {
  OFF_WQTH  = 0*MB,  OFF_WQTL  = 2*MB,
  OFF_WDKVH = 4*MB,  OFF_WDKVL = 4*MB + 512*1024,
  OFF_WUKH  = 5*MB,  OFF_WUKL  = 5*MB + 512*1024,
  OFF_WUVH  = 6*MB,  OFF_WUVL  = 6*MB + 512*1024,
  OFF_WOTH  = 7*MB,  OFF_WOTL  = 9*MB,
  OFF_W1T   = 11*MB, OFF_W3T   = 15*MB, OFF_W2T = 19*MB,
  OFF_X1H   = 23*MB, OFF_X1L   = 31*MB,          // dead after c-gemm
  OFF_QTH   = 39*MB, OFF_QTL   = 47*MB,
  OFF_CH    = 55*MB, OFF_CL    = 57*MB,
  OFF_KTH   = 59*MB, OFF_KTL   = 67*MB,
  OFF_VTOKH = 75*MB, OFF_VTOKL = 83*MB,          // v token-major (dead after v_tr)
  // aliases (time-disjoint):
  OFF_VT_H  = 23*MB, OFF_VT_L  = 31*MB,          // V^T [bh][64][2048] (X1 dead)
  OFF_AOH   = 75*MB, OFF_AOL   = 83*MB,          // attn out (VTOK dead)
  OFF_XMID  = 39*MB,                             // f32 16MB (QT dead)
  OFF_X2    = 55*MB,                             // bf16 8MB (C/KTH dead)
  OFF_H1    = 23*MB,                             // 16MB (VT dead)
  OFF_H3    = 39*MB,                             // 16MB (XMID dead after router)
  OFF_INVT  = 91*MB,
  OFF_INVR  = 91*MB + 4096,
  OFF_GATES = 91*MB + 32768,
  WS_NEEDED = 91*MB + 262144
};

extern "C" void kernel_launch(void* const* d_in, const int* in_sizes, int n_in,
                              void* d_out, int out_size, void* d_ws, size_t ws_size,
                              hipStream_t stream) {
  const float* x     = (const float*)d_in[0];
  const int*   pos   = (const int*)d_in[1];
  const float* n1w   = (const float*)d_in[2];
  const float* wq    = (const float*)d_in[3];
  const float* wdkv  = (const float*)d_in[4];
  const float* wuk   = (const float*)d_in[5];
  const float* wuv   = (const float*)d_in[6];
  const float* wo    = (const float*)d_in[7];
  const float* n2w   = (const float*)d_in[8];
  const float* wr    = (const float*)d_in[9];
  const float* rbias = (const float*)d_in[10];
  const float* w1    = (const float*)d_in[11];
  const float* w3    = (const float*)d_in[12];
  const float* w2    = (const float*)d_in[13];
  float* out = (float*)d_out;
  char* ws = (char*)d_ws;
  if (ws_size < WS_NEEDED) return;

  short *WQTH=(short*)(ws+OFF_WQTH), *WQTL=(short*)(ws+OFF_WQTL);
  short *WDKVH=(short*)(ws+OFF_WDKVH), *WDKVL=(short*)(ws+OFF_WDKVL);
  short *WUKH=(short*)(ws+OFF_WUKH), *WUKL=(short*)(ws+OFF_WUKL);
  short *WUVH=(short*)(ws+OFF_WUVH), *WUVL=(short*)(ws+OFF_WUVL);
  short *WOTH=(short*)(ws+OFF_WOTH), *WOTL=(short*)(ws+OFF_WOTL);
  short *W1T=(short*)(ws+OFF_W1T), *W3T=(short*)(ws+OFF_W3T), *W2T=(short*)(ws+OFF_W2T);
  short *X1H=(short*)(ws+OFF_X1H), *X1L=(short*)(ws+OFF_X1L);
  short *QTH=(short*)(ws+OFF_QTH), *QTL=(short*)(ws+OFF_QTL);
  short *CH=(short*)(ws+OFF_CH),   *CL=(short*)(ws+OFF_CL);
  short *KTH=(short*)(ws+OFF_KTH), *KTL=(short*)(ws+OFF_KTL);
  short *VTOKH=(short*)(ws+OFF_VTOKH), *VTOKL=(short*)(ws+OFF_VTOKL);
  short *VT_H=(short*)(ws+OFF_VT_H), *VT_L=(short*)(ws+OFF_VT_L);
  short *AOH=(short*)(ws+OFF_AOH), *AOL=(short*)(ws+OFF_AOL);
  float *XMID=(float*)(ws+OFF_XMID);
  short *X2=(short*)(ws+OFF_X2);
  short *H1=(short*)(ws+OFF_H1), *H3=(short*)(ws+OFF_H3);
  float *INVT=(float*)(ws+OFF_INVT), *INVR=(float*)(ws+OFF_INVR), *GATES=(float*)(ws+OFF_GATES);

  invtab_kernel<<<1, 64, 0, stream>>>(INVT);
  rmsnorm_kernel<<<4096, 256, 0, stream>>>(x, n1w, X1H, X1L, nullptr, nullptr);
  transpose_conv_kernel<true ><<<dim3(32,32,1), 256, 0, stream>>>(wq,   WQTH, WQTL, 1024, 1024);
  transpose_conv_kernel<true ><<<dim3( 8,32,1), 256, 0, stream>>>(wdkv, WDKVH, WDKVL, 1024, 256);
  transpose_conv_kernel<true ><<<dim3(32, 8,1), 256, 0, stream>>>(wuk,  WUKH, WUKL, 256, 1024);
  transpose_conv_kernel<true ><<<dim3(32, 8,1), 256, 0, stream>>>(wuv,  WUVH, WUVL, 256, 1024);
  transpose_conv_kernel<true ><<<dim3(32,32,1), 256, 0, stream>>>(wo,   WOTH, WOTL, 1024, 1024);
  transpose_conv_kernel<false><<<dim3( 8,32,8), 256, 0, stream>>>(w1,   W1T, nullptr, 1024, 256);
  transpose_conv_kernel<false><<<dim3( 8,32,8), 256, 0, stream>>>(w3,   W3T, nullptr, 1024, 256);
  transpose_conv_kernel<false><<<dim3(32, 8,8), 256, 0, stream>>>(w2,   W2T, nullptr, 256, 1024);
  gemm_split_kernel<0><<<dim3(32,8), 256, 0, stream>>>(X1H, X1L, WQTH, WQTL, QTH, QTL, nullptr, nullptr, 4096, 1024, 1024);
  gemm_split_kernel<0><<<dim3(32,2), 256, 0, stream>>>(X1H, X1L, WDKVH, WDKVL, CH, CL, nullptr, nullptr, 4096, 256, 1024);
  gemm_split_kernel<0><<<dim3(32,8), 256, 0, stream>>>(CH, CL, WUKH, WUKL, KTH, KTL, nullptr, nullptr, 4096, 1024, 256);
  gemm_split_kernel<0><<<dim3(32,8), 256, 0, stream>>>(CH, CL, WUVH, WUVL, VTOKH, VTOKL, nullptr, nullptr, 4096, 1024, 256);
  v_tr_kernel<<<dim3(32,32), 256, 0, stream>>>(VTOKH, VTOKL, VT_H, VT_L);
  rope_inplace_kernel<<<4096, 256, 0, stream>>>(QTH, QTL, KTH, KTL, pos, INVT);
  attn_kernel<<<dim3(32,32), 256, 0, stream>>>(QTH, QTL, KTH, KTL, VT_H, VT_L, AOH, AOL);
  gemm_split_kernel<1><<<dim3(32,8), 256, 0, stream>>>(AOH, AOL, WOTH, WOTL, nullptr, nullptr, XMID, x, 4096, 1024, 1024);
  rmsnorm_kernel<<<4096, 256, 0, stream>>>(XMID, n2w, X2, nullptr, INVR, out);
  router_kernel<<<4096, 256, 0, stream>>>(XMID, INVR, n2w, wr, rbias, GATES);
  gemm_bt_kernel<0><<<dim3(32,2,8), 256, 0, stream>>>(X2, W1T, H1, nullptr, 0, 4096, 256, 1024, 262144, 1048576);
  gemm_bt_kernel<0><<<dim3(32,2,8), 256, 0, stream>>>(X2, W3T, H3, nullptr, 0, 4096, 256, 1024, 262144, 1048576);
  silu_mul_kernel<<<4096, 256, 0, stream>>>(H1, H3, H1);
  for (int e = 0; e < 8; ++e)
    gemm_bt_kernel<2><<<dim3(32,8,1), 256, 0, stream>>>(H1 + (size_t)e * 1048576,
                                                        W2T + (size_t)e * 262144,
                                                        out, GATES, e,
                                                        4096, 1024, 256, 0, 0);
}

// Round 6
// 604.328 us; speedup vs baseline: 1.9883x; 1.1542x over previous
//
#include <hip/hip_runtime.h>
#include <hip/hip_bf16.h>
#include <math.h>

// DeepSeekV3-style block: rmsnorm -> MLA attn -> residual -> rmsnorm -> MoE -> residual
// B=2 S=2048 D=1024 H=16 HD=64 R=256 E=8 K=2 MH=256
//
// Precision: attention path (x1 -> q,c,k,v -> attn -> @wo -> xmid) in emulated fp32
// (bf16 hi/lo pairs, 3-term MFMA) so router top-2 doesn't flip. MoE path plain bf16.
// MoE: h1/h3 dense GEMMs -> token-major h' = gate*silu(h1)*h3 -> ONE stacked GEMM
// out = xmid + h'[4096,2048] @ W2S[1024,2048]^T   (replaces 8 RMW dispatches).

typedef __attribute__((ext_vector_type(8))) short short8;
typedef __attribute__((ext_vector_type(4))) float f32x4;

static __device__ __forceinline__ float bf2f(short s) {
  union { unsigned u; float f; } c; c.u = ((unsigned)(unsigned short)s) << 16; return c.f;
}
static __device__ __forceinline__ short f2bf(float f) {
  __hip_bfloat16 h = __float2bfloat16(f);
  short s; __builtin_memcpy(&s, &h, sizeof(s)); return s;
}
static __device__ __forceinline__ void split2(float v, short& hi, short& lo) {
  hi = f2bf(v); lo = f2bf(v - bf2f(hi));
}

// ---------------- RoPE inv-freq table, bit-faithful to numpy f32 -------------------------
__global__ void invtab_kernel(float* __restrict__ tab) {
  int j = threadIdx.x;
  if (j < 32) {
    float t = (float)pow(10000.0, (double)j * (1.0 / 32.0));
    tab[j] = 1.0f / t;
  }
}

// ---------------- rmsnorm: f32 in -> bf16 hi (+optional lo, invrms) ----------------------
__global__ __launch_bounds__(256) void rmsnorm_kernel(
    const float* __restrict__ in, const float* __restrict__ w,
    short* __restrict__ outH, short* __restrict__ outL,
    float* __restrict__ invrms)
{
  int row = blockIdx.x, tid = threadIdx.x;
  const float4* xv = (const float4*)(in + (size_t)row * 1024);
  float4 v = xv[tid];
  float ss = v.x*v.x + v.y*v.y + v.z*v.z + v.w*v.w;
  #pragma unroll
  for (int off = 32; off > 0; off >>= 1) ss += __shfl_down(ss, off);
  __shared__ float wsum[4];
  if ((tid & 63) == 0) wsum[tid >> 6] = ss;
  __syncthreads();
  float inv = rsqrtf((wsum[0] + wsum[1] + wsum[2] + wsum[3]) * (1.0f/1024.0f) + 1e-6f);
  float4 wv = ((const float4*)w)[tid];
  size_t base = (size_t)row * 1024 + (size_t)tid * 4;
  float r[4] = { v.x*inv*wv.x, v.y*inv*wv.y, v.z*inv*wv.z, v.w*inv*wv.w };
  #pragma unroll
  for (int j = 0; j < 4; ++j) {
    short hi, lo; split2(r[j], hi, lo);
    outH[base + j] = hi;
    if (outL) outL[base + j] = lo;
  }
  if (invrms && tid == 0) invrms[row] = inv;
}

// ---------------- transpose+convert: f32 (K,N) -> bf16 (N,K)-ish, generalized ------------
// out index = z*zso + n*ldo + k.  Normal: zso=K*N, ldo=K.  W2-stacked: zso=256, ldo=2048.
template<bool SPLIT>
__global__ __launch_bounds__(256) void transpose_conv_kernel(
    const float* __restrict__ in, short* __restrict__ outH, short* __restrict__ outL,
    int K, int N, long zso, long ldo)
{
  __shared__ float tile[32][33];
  const float* ip = in + (size_t)blockIdx.z * K * N;
  size_t ob = (size_t)blockIdx.z * zso;
  int bn = blockIdx.x * 32, bk = blockIdx.y * 32;
  int tx = threadIdx.x & 31, ty = threadIdx.x >> 5;
  #pragma unroll
  for (int i = 0; i < 32; i += 8)
    tile[ty + i][tx] = ip[(size_t)(bk + ty + i) * N + bn + tx];
  __syncthreads();
  #pragma unroll
  for (int i = 0; i < 32; i += 8) {
    float v = tile[tx][ty + i];
    size_t oi = ob + (size_t)(bn + ty + i) * ldo + bk + tx;
    short hi, lo; split2(v, hi, lo);
    outH[oi] = hi;
    if (SPLIT) outL[oi] = lo;
  }
}

// ---------------- split GEMM: C = (AH+AL)[M,K] @ (BH+BL)[N,K]^T, 3-term emulated f32 -----
template<int EPI>
__global__ __launch_bounds__(256) void gemm_split_kernel(
    const short* __restrict__ AH, const short* __restrict__ AL,
    const short* __restrict__ BH, const short* __restrict__ BL,
    short* __restrict__ CH, short* __restrict__ CL,
    float* __restrict__ Cf, const float* __restrict__ res,
    int M, int N, int K)
{
  __shared__ __align__(16) short AsH[128*32], AsL[128*32], BsH[128*32], BsL[128*32];
  int bm = blockIdx.x * 128, bn = blockIdx.y * 128;
  int tid = threadIdx.x;
  int wave = tid >> 6, lane = tid & 63;
  int g = lane >> 4, r16 = lane & 15;
  int wr = wave >> 1, wc = wave & 1;
  f32x4 acc[4][4];
  #pragma unroll
  for (int m = 0; m < 4; ++m)
    #pragma unroll
    for (int n = 0; n < 4; ++n) acc[m][n] = (f32x4){0.f,0.f,0.f,0.f};
  int flat0 = tid * 8;
  for (int k0 = 0; k0 < K; k0 += 32) {
    __syncthreads();
    #pragma unroll
    for (int it = 0; it < 2; ++it) {
      int flat = it * 2048 + flat0;
      int row = flat >> 5, col = flat & 31;
      size_t ga = (size_t)(bm + row) * K + k0 + col;
      size_t gb = (size_t)(bn + row) * K + k0 + col;
      int lo = it * 4096 + wave * 1024;
      __builtin_amdgcn_global_load_lds((__attribute__((address_space(1))) void*)(AH + ga),
                                       (__attribute__((address_space(3))) void*)((char*)AsH + lo), 16, 0, 0);
      __builtin_amdgcn_global_load_lds((__attribute__((address_space(1))) void*)(AL + ga),
                                       (__attribute__((address_space(3))) void*)((char*)AsL + lo), 16, 0, 0);
      __builtin_amdgcn_global_load_lds((__attribute__((address_space(1))) void*)(BH + gb),
                                       (__attribute__((address_space(3))) void*)((char*)BsH + lo), 16, 0, 0);
      __builtin_amdgcn_global_load_lds((__attribute__((address_space(1))) void*)(BL + gb),
                                       (__attribute__((address_space(3))) void*)((char*)BsL + lo), 16, 0, 0);
    }
    __syncthreads();
    short8 afh[4], afl[4], bfh[4], bfl[4];
    #pragma unroll
    for (int m = 0; m < 4; ++m) {
      int off = (64*wr + 16*m + r16) * 32 + g * 8;
      afh[m] = *(const short8*)(AsH + off);
      afl[m] = *(const short8*)(AsL + off);
    }
    #pragma unroll
    for (int n = 0; n < 4; ++n) {
      int off = (64*wc + 16*n + r16) * 32 + g * 8;
      bfh[n] = *(const short8*)(BsH + off);
      bfl[n] = *(const short8*)(BsL + off);
    }
    #pragma unroll
    for (int m = 0; m < 4; ++m)
      #pragma unroll
      for (int n = 0; n < 4; ++n) {
        acc[m][n] = __builtin_amdgcn_mfma_f32_16x16x32_bf16(afh[m], bfh[n], acc[m][n], 0, 0, 0);
        acc[m][n] = __builtin_amdgcn_mfma_f32_16x16x32_bf16(afh[m], bfl[n], acc[m][n], 0, 0, 0);
        acc[m][n] = __builtin_amdgcn_mfma_f32_16x16x32_bf16(afl[m], bfh[n], acc[m][n], 0, 0, 0);
      }
  }
  #pragma unroll
  for (int m = 0; m < 4; ++m)
    #pragma unroll
    for (int n = 0; n < 4; ++n)
      #pragma unroll
      for (int r = 0; r < 4; ++r) {
        int row = bm + 64*wr + 16*m + g*4 + r;
        int col = bn + 64*wc + 16*n + r16;
        size_t idx = (size_t)row * N + col;
        float v = acc[m][n][r];
        if (EPI == 0) {
          short hi, lo; split2(v, hi, lo);
          CH[idx] = hi; CL[idx] = lo;
        } else {
          Cf[idx] = v + res[idx];
        }
      }
}

// ---------------- plain bf16 GEMM (MoE path) ---------------------------------------------
// EPI 0: bf16 store at z*sC + row*ldC + col.  EPI 1: f32 C = acc + res (z must be 1).
template<int EPI>
__global__ __launch_bounds__(256) void gemm_bt_kernel(
    const short* __restrict__ A, const short* __restrict__ Bt, void* __restrict__ Cv,
    const float* __restrict__ res,
    int M, int N, int K, long sBt, long sC, long ldC)
{
  __shared__ __align__(16) short As[128*32];
  __shared__ __align__(16) short Bs[128*32];
  int z = blockIdx.z;
  const short* Ab = A;
  const short* Bb = Bt + (size_t)z * sBt;
  int bm = blockIdx.x * 128, bn = blockIdx.y * 128;
  int tid = threadIdx.x;
  int wave = tid >> 6, lane = tid & 63;
  int g = lane >> 4, r16 = lane & 15;
  int wr = wave >> 1, wc = wave & 1;
  f32x4 acc[4][4];
  #pragma unroll
  for (int m = 0; m < 4; ++m)
    #pragma unroll
    for (int n = 0; n < 4; ++n) acc[m][n] = (f32x4){0.f,0.f,0.f,0.f};
  int flat0 = tid * 8;
  for (int k0 = 0; k0 < K; k0 += 32) {
    __syncthreads();
    #pragma unroll
    for (int it = 0; it < 2; ++it) {
      int flat = it * 2048 + flat0;
      int row = flat >> 5, col = flat & 31;
      const short* ga = Ab + (size_t)(bm + row) * K + k0 + col;
      const short* gb = Bb + (size_t)(bn + row) * K + k0 + col;
      char* la = (char*)As + it * 4096 + wave * 1024;
      char* lb = (char*)Bs + it * 4096 + wave * 1024;
      __builtin_amdgcn_global_load_lds((__attribute__((address_space(1))) void*)ga,
                                       (__attribute__((address_space(3))) void*)la, 16, 0, 0);
      __builtin_amdgcn_global_load_lds((__attribute__((address_space(1))) void*)gb,
                                       (__attribute__((address_space(3))) void*)lb, 16, 0, 0);
    }
    __syncthreads();
    short8 af[4], bfv[4];
    #pragma unroll
    for (int m = 0; m < 4; ++m)
      af[m] = *(const short8*)(As + (64*wr + 16*m + r16) * 32 + g * 8);
    #pragma unroll
    for (int n = 0; n < 4; ++n)
      bfv[n] = *(const short8*)(Bs + (64*wc + 16*n + r16) * 32 + g * 8);
    #pragma unroll
    for (int m = 0; m < 4; ++m)
      #pragma unroll
      for (int n = 0; n < 4; ++n)
        acc[m][n] = __builtin_amdgcn_mfma_f32_16x16x32_bf16(af[m], bfv[n], acc[m][n], 0, 0, 0);
  }
  #pragma unroll
  for (int m = 0; m < 4; ++m)
    #pragma unroll
    for (int n = 0; n < 4; ++n)
      #pragma unroll
      for (int r = 0; r < 4; ++r) {
        int row = bm + 64*wr + 16*m + g*4 + r;
        int col = bn + 64*wc + 16*n + r16;
        float v = acc[m][n][r];
        if (EPI == 0) {
          ((short*)Cv)[(size_t)z * sC + (size_t)row * ldC + col] = f2bf(v);
        } else {
          size_t idx = (size_t)row * N + col;
          ((float*)Cv)[idx] = v + res[idx];
        }
      }
}

// ---------------- RoPE in-place on split q,k (token-major B,S,H,HD) ----------------------
__global__ __launch_bounds__(256) void rope_inplace_kernel(
    short* __restrict__ QH, short* __restrict__ QL,
    short* __restrict__ KH, short* __restrict__ KL,
    const int* __restrict__ pos_ids, const float* __restrict__ invtab)
{
  int token = blockIdx.x, tid = threadIdx.x;
  float pos = (float)pos_ids[token];
  #pragma unroll
  for (int it = 0; it < 2; ++it) {
    int p = it * 256 + tid;
    int h = p >> 5, j = p & 31;
    float ang = pos * invtab[j];
    float sn, cs; sincosf(ang, &sn, &cs);
    size_t i1 = (size_t)token * 1024 + h * 64 + j;
    size_t i2 = i1 + 32;
    float q1 = bf2f(QH[i1]) + bf2f(QL[i1]);
    float q2 = bf2f(QH[i2]) + bf2f(QL[i2]);
    float a = q1 * cs - q2 * sn, bq = q1 * sn + q2 * cs;
    short hi, lo;
    split2(a,  hi, lo); QH[i1] = hi; QL[i1] = lo;
    split2(bq, hi, lo); QH[i2] = hi; QL[i2] = lo;
    float k1 = bf2f(KH[i1]) + bf2f(KL[i1]);
    float k2 = bf2f(KH[i2]) + bf2f(KL[i2]);
    a = k1 * cs - k2 * sn; bq = k1 * sn + k2 * cs;
    split2(a,  hi, lo); KH[i1] = hi; KL[i1] = lo;
    split2(bq, hi, lo); KH[i2] = hi; KL[i2] = lo;
  }
}

// ---------------- V transpose: token-major (b,s,h,d) -> VT[bh][d=64][s=2048] -------------
__global__ __launch_bounds__(256) void v_tr_kernel(
    const short* __restrict__ VH, const short* __restrict__ VL,
    short* __restrict__ TH, short* __restrict__ TL)
{
  __shared__ short th[64][80], tl[64][80];
  int s0 = blockIdx.x * 64, bh = blockIdx.y;
  int b = bh >> 4, h = bh & 15;
  int tid = threadIdx.x;
  #pragma unroll
  for (int p = 0; p < 2; ++p) {
    int flat = p * 256 + tid;
    int sr = flat >> 3, ck = flat & 7;
    size_t gi = ((size_t)((b * 2048) + s0 + sr) * 16 + h) * 64 + ck * 8;
    short8 vh = *(const short8*)(VH + gi);
    short8 vl = *(const short8*)(VL + gi);
    #pragma unroll
    for (int i = 0; i < 8; ++i) { th[sr][ck*8+i] = vh[i]; tl[sr][ck*8+i] = vl[i]; }
  }
  __syncthreads();
  #pragma unroll
  for (int p = 0; p < 2; ++p) {
    int flat = p * 256 + tid;
    int dr = flat >> 3, sc = flat & 7;
    short8 rh, rl;
    #pragma unroll
    for (int i = 0; i < 8; ++i) { rh[i] = th[sc*8+i][dr]; rl[i] = tl[sc*8+i][dr]; }
    size_t go = ((size_t)bh * 64 + dr) * 2048 + s0 + sc * 8;
    *(short8*)(TH + go) = rh;
    *(short8*)(TL + go) = rl;
  }
}

// ---------------- causal flash attention, split precision --------------------------------
// 4 waves/block, 64-row q-tile (16 rows/wave), KVBLK=64, K row-major + V^T in LDS.
// Swapped QK^T: S^T = mfma(K, Q) (rows=kv, cols=q); per-lane-column softmax.
__global__ __launch_bounds__(256) void attn_kernel(
    const short* __restrict__ QH, const short* __restrict__ QL,
    const short* __restrict__ KH, const short* __restrict__ KL,
    const short* __restrict__ VTH, const short* __restrict__ VTL,
    short* __restrict__ OH, short* __restrict__ OL)
{
  __shared__ __align__(16) char ksH[8192], ksL[8192], vtH[8192], vtL[8192];
  int qt = gridDim.x - 1 - blockIdx.x;       // LPT: longest blocks first
  int qb = qt * 64;
  int bh = blockIdx.y;
  int b = bh >> 4, h = bh & 15;
  int tid = threadIdx.x;
  int w = tid >> 6, lane = tid & 63;
  int g = lane >> 4, r16 = lane & 15;
  auto gidx = [&](int s, int d) -> size_t {
    return ((size_t)(b * 2048 + s) * 16 + h) * 64 + d;
  };
  int qrow = qb + 16 * w + r16;
  short8 qf0h = *(const short8*)(QH + gidx(qrow, g * 8));
  short8 qf0l = *(const short8*)(QL + gidx(qrow, g * 8));
  short8 qf1h = *(const short8*)(QH + gidx(qrow, 32 + g * 8));
  short8 qf1l = *(const short8*)(QL + gidx(qrow, 32 + g * 8));
  f32x4 o[4];
  #pragma unroll
  for (int c = 0; c < 4; ++c) o[c] = (f32x4){0.f,0.f,0.f,0.f};
  float mrun = -1e30f, lsum = 0.f;
  int qi = qrow;
  int nt = qt + 1;
  for (int t = 0; t < nt; ++t) {
    int kvb = t * 64;
    __syncthreads();
    #pragma unroll
    for (int i = 0; i < 2; ++i) {
      int wi = w * 2 + i;
      int row = wi * 8 + (lane >> 3);
      int cs = (lane & 7) ^ (row & 7);
      size_t gk = gidx(kvb + row, cs * 8);
      size_t gv = ((size_t)bh * 64 + row) * 2048 + kvb + cs * 8;
      int lb = wi * 1024;
      __builtin_amdgcn_global_load_lds((__attribute__((address_space(1))) void*)(KH + gk),
                                       (__attribute__((address_space(3))) void*)(ksH + lb), 16, 0, 0);
      __builtin_amdgcn_global_load_lds((__attribute__((address_space(1))) void*)(KL + gk),
                                       (__attribute__((address_space(3))) void*)(ksL + lb), 16, 0, 0);
      __builtin_amdgcn_global_load_lds((__attribute__((address_space(1))) void*)(VTH + gv),
                                       (__attribute__((address_space(3))) void*)(vtH + lb), 16, 0, 0);
      __builtin_amdgcn_global_load_lds((__attribute__((address_space(1))) void*)(VTL + gv),
                                       (__attribute__((address_space(3))) void*)(vtL + lb), 16, 0, 0);
    }
    __syncthreads();
    float p16[16]; float tm = -1e30f;
    #pragma unroll
    for (int T = 0; T < 4; ++T) {
      int krow = 16 * T + r16;
      int swz = (r16 & 7) << 4;
      short8 k0h = *(const short8*)(ksH + krow * 128 + ((16 * g) ^ swz));
      short8 k0l = *(const short8*)(ksL + krow * 128 + ((16 * g) ^ swz));
      short8 k1h = *(const short8*)(ksH + krow * 128 + ((64 + 16 * g) ^ swz));
      short8 k1l = *(const short8*)(ksL + krow * 128 + ((64 + 16 * g) ^ swz));
      f32x4 a = (f32x4){0.f,0.f,0.f,0.f};
      a = __builtin_amdgcn_mfma_f32_16x16x32_bf16(k0h, qf0h, a, 0, 0, 0);
      a = __builtin_amdgcn_mfma_f32_16x16x32_bf16(k0h, qf0l, a, 0, 0, 0);
      a = __builtin_amdgcn_mfma_f32_16x16x32_bf16(k0l, qf0h, a, 0, 0, 0);
      a = __builtin_amdgcn_mfma_f32_16x16x32_bf16(k1h, qf1h, a, 0, 0, 0);
      a = __builtin_amdgcn_mfma_f32_16x16x32_bf16(k1h, qf1l, a, 0, 0, 0);
      a = __builtin_amdgcn_mfma_f32_16x16x32_bf16(k1l, qf1h, a, 0, 0, 0);
      #pragma unroll
      for (int r = 0; r < 4; ++r) {
        float sv = a[r] * 0.125f;
        int kvi = kvb + 16 * T + 4 * g + r;
        sv = (kvi > qi) ? -1e30f : sv;
        p16[T * 4 + r] = sv;
        tm = fmaxf(tm, sv);
      }
    }
    tm = fmaxf(tm, __shfl_xor(tm, 16));
    tm = fmaxf(tm, __shfl_xor(tm, 32));
    float mnew = fmaxf(mrun, tm);
    float sf = __expf(mrun - mnew);
    float ps = 0.f;
    #pragma unroll
    for (int i2 = 0; i2 < 16; ++i2) { p16[i2] = __expf(p16[i2] - mnew); ps += p16[i2]; }
    ps += __shfl_xor(ps, 16);
    ps += __shfl_xor(ps, 32);
    lsum = lsum * sf + ps;
    mrun = mnew;
    float sfr[4];
    #pragma unroll
    for (int r = 0; r < 4; ++r) sfr[r] = __shfl(sf, 4 * g + r);
    #pragma unroll
    for (int c = 0; c < 4; ++c)
      #pragma unroll
      for (int r = 0; r < 4; ++r) o[c][r] *= sfr[r];
    short8 pah[2], pal[2];
    #pragma unroll
    for (int h2 = 0; h2 < 2; ++h2) {
      #pragma unroll
      for (int j = 0; j < 8; ++j) {
        int src = (((2 * g + (j >> 2)) & 3) << 4) + r16;
        float v0 = __shfl(p16[(2 * h2) * 4 + (j & 3)], src);
        float v1 = __shfl(p16[(2 * h2 + 1) * 4 + (j & 3)], src);
        float pv = (g >= 2) ? v1 : v0;
        short phi, plo; split2(pv, phi, plo);
        pah[h2][j] = phi; pal[h2][j] = plo;
      }
    }
    #pragma unroll
    for (int c = 0; c < 4; ++c) {
      #pragma unroll
      for (int h2 = 0; h2 < 2; ++h2) {
        int bo = (16 * c + r16) * 128 + ((64 * h2 + 16 * g) ^ ((r16 & 7) << 4));
        short8 vbh = *(const short8*)(vtH + bo);
        short8 vbl = *(const short8*)(vtL + bo);
        o[c] = __builtin_amdgcn_mfma_f32_16x16x32_bf16(pah[h2], vbh, o[c], 0, 0, 0);
        o[c] = __builtin_amdgcn_mfma_f32_16x16x32_bf16(pah[h2], vbl, o[c], 0, 0, 0);
        o[c] = __builtin_amdgcn_mfma_f32_16x16x32_bf16(pal[h2], vbh, o[c], 0, 0, 0);
      }
    }
  }
  float lr[4];
  #pragma unroll
  for (int r = 0; r < 4; ++r) lr[r] = __shfl(lsum, 4 * g + r);
  #pragma unroll
  for (int c = 0; c < 4; ++c)
    #pragma unroll
    for (int r = 0; r < 4; ++r) {
      int q = qb + 16 * w + 4 * g + r;
      int d = 16 * c + r16;
      float v = o[c][r] / lr[r];
      short hi, lo; split2(v, hi, lo);
      size_t oi = gidx(q, d);
      OH[oi] = hi; OL[oi] = lo;
    }
}

// ---------------- router: f32 rmsnorm'd xmid @ wr -> sigmoid -> biased top2 -> gates -----
__global__ __launch_bounds__(256) void router_kernel(
    const float* __restrict__ xmid, const float* __restrict__ invrms,
    const float* __restrict__ w2norm, const float* __restrict__ wr,
    const float* __restrict__ rbias, float* __restrict__ gates)
{
  int row = blockIdx.x, tid = threadIdx.x;
  float invr = invrms[row];
  float part[8] = {0,0,0,0,0,0,0,0};
  for (int d = tid; d < 1024; d += 256) {
    float xv = xmid[(size_t)row * 1024 + d] * invr * w2norm[d];
    #pragma unroll
    for (int e = 0; e < 8; ++e) part[e] += xv * wr[d * 8 + e];
  }
  #pragma unroll
  for (int e = 0; e < 8; ++e)
    #pragma unroll
    for (int off = 32; off > 0; off >>= 1) part[e] += __shfl_down(part[e], off);
  __shared__ float red[4][8];
  if ((tid & 63) == 0)
    #pragma unroll
    for (int e = 0; e < 8; ++e) red[tid >> 6][e] = part[e];
  __syncthreads();
  if (tid == 0) {
    float sc[8], bs[8];
    #pragma unroll
    for (int e = 0; e < 8; ++e) {
      float t = red[0][e] + red[1][e] + red[2][e] + red[3][e];
      sc[e] = 1.f / (1.f + expf(-t));
      bs[e] = sc[e] + rbias[e];
    }
    int i0 = 0;
    #pragma unroll
    for (int e = 1; e < 8; ++e) if (bs[e] > bs[i0]) i0 = e;
    int i1 = -1;
    #pragma unroll
    for (int e = 0; e < 8; ++e) if (e != i0 && (i1 < 0 || bs[e] > bs[i1])) i1 = e;
    float s0 = sc[i0], s1 = sc[i1];
    float den = s0 + s1 + 1e-9f;
    #pragma unroll
    for (int e = 0; e < 8; ++e)
      gates[(size_t)row * 8 + e] = (e == i0) ? s0 / den : ((e == i1) ? s1 / den : 0.f);
  }
}

// ---------------- h' = gate * silu(h1) * h3, token-major [4096][2048], in-place on h1 ----
__global__ __launch_bounds__(256) void silu_gate_kernel(
    const short* __restrict__ h1, const short* __restrict__ h3,
    const float* __restrict__ gates, short* __restrict__ h)
{
  size_t i = ((size_t)blockIdx.x * 256 + threadIdx.x) * 8;
  int t = (int)(i >> 11);
  int e = (int)((i >> 8) & 7);
  float gv = gates[(size_t)t * 8 + e];
  short8 a = *(const short8*)(h1 + i);
  short8 b3 = *(const short8*)(h3 + i);
  short8 r;
  #pragma unroll
  for (int j = 0; j < 8; ++j) {
    float x = bf2f(a[j]);
    float y = bf2f(b3[j]);
    r[j] = f2bf(gv * (x / (1.f + expf(-x))) * y);
  }
  *(short8*)(h + i) = r;
}

// ---------------- workspace layout (1 MB = 1048576 B) ------------------------------------
#define MB (1048576ull)
enum : unsigned long long {
  OFF_WQTH  = 0*MB,  OFF_WQTL  = 2*MB,
  OFF_WDKVH = 4*MB,  OFF_WDKVL = 4*MB + 512*1024,
  OFF_WUKH  = 5*MB,  OFF_WUKL  = 5*MB + 512*1024,
  OFF_WUVH  = 6*MB,  OFF_WUVL  = 6*MB + 512*1024,
  OFF_WOTH  = 7*MB,  OFF_WOTL  = 9*MB,
  OFF_W1T   = 11*MB, OFF_W3T   = 15*MB, OFF_W2S = 19*MB,   // W2S: [1024][e*256+k] 4MB
  OFF_X1H   = 23*MB, OFF_X1L   = 31*MB,
  OFF_QTH   = 39*MB, OFF_QTL   = 47*MB,
  OFF_CH    = 55*MB, OFF_CL    = 57*MB,
  OFF_KTH   = 59*MB, OFF_KTL   = 67*MB,
  OFF_VTOKH = 75*MB, OFF_VTOKL = 83*MB,
  // aliases (time-disjoint):
  OFF_VT_H  = 23*MB, OFF_VT_L  = 31*MB,          // V^T (X1 dead after q/c gemms)
  OFF_AOH   = 75*MB, OFF_AOL   = 83*MB,          // attn out (VTOK dead after v_tr)
  OFF_XMID  = 39*MB,                             // f32 16MB (QT dead after attn); live to end
  OFF_X2    = 55*MB,                             // bf16 8MB (C dead, KTH head dead after attn)
  OFF_H1    = 23*MB,                             // [4096][2048] bf16 16MB (VT dead after attn)
  OFF_H3    = 75*MB,                             // [4096][2048] bf16 16MB (AO dead after wo gemm)
  OFF_INVT  = 91*MB,
  OFF_INVR  = 91*MB + 4096,
  OFF_GATES = 91*MB + 32768,
  WS_NEEDED = 91*MB + 262144
};

extern "C" void kernel_launch(void* const* d_in, const int* in_sizes, int n_in,
                              void* d_out, int out_size, void* d_ws, size_t ws_size,
                              hipStream_t stream) {
  const float* x     = (const float*)d_in[0];
  const int*   pos   = (const int*)d_in[1];
  const float* n1w   = (const float*)d_in[2];
  const float* wq    = (const float*)d_in[3];
  const float* wdkv  = (const float*)d_in[4];
  const float* wuk   = (const float*)d_in[5];
  const float* wuv   = (const float*)d_in[6];
  const float* wo    = (const float*)d_in[7];
  const float* n2w   = (const float*)d_in[8];
  const float* wr    = (const float*)d_in[9];
  const float* rbias = (const float*)d_in[10];
  const float* w1    = (const float*)d_in[11];
  const float* w3    = (const float*)d_in[12];
  const float* w2    = (const float*)d_in[13];
  float* out = (float*)d_out;
  char* ws = (char*)d_ws;
  if (ws_size < WS_NEEDED) return;

  short *WQTH=(short*)(ws+OFF_WQTH), *WQTL=(short*)(ws+OFF_WQTL);
  short *WDKVH=(short*)(ws+OFF_WDKVH), *WDKVL=(short*)(ws+OFF_WDKVL);
  short *WUKH=(short*)(ws+OFF_WUKH), *WUKL=(short*)(ws+OFF_WUKL);
  short *WUVH=(short*)(ws+OFF_WUVH), *WUVL=(short*)(ws+OFF_WUVL);
  short *WOTH=(short*)(ws+OFF_WOTH), *WOTL=(short*)(ws+OFF_WOTL);
  short *W1T=(short*)(ws+OFF_W1T), *W3T=(short*)(ws+OFF_W3T), *W2S=(short*)(ws+OFF_W2S);
  short *X1H=(short*)(ws+OFF_X1H), *X1L=(short*)(ws+OFF_X1L);
  short *QTH=(short*)(ws+OFF_QTH), *QTL=(short*)(ws+OFF_QTL);
  short *CH=(short*)(ws+OFF_CH),   *CL=(short*)(ws+OFF_CL);
  short *KTH=(short*)(ws+OFF_KTH), *KTL=(short*)(ws+OFF_KTL);
  short *VTOKH=(short*)(ws+OFF_VTOKH), *VTOKL=(short*)(ws+OFF_VTOKL);
  short *VT_H=(short*)(ws+OFF_VT_H), *VT_L=(short*)(ws+OFF_VT_L);
  short *AOH=(short*)(ws+OFF_AOH), *AOL=(short*)(ws+OFF_AOL);
  float *XMID=(float*)(ws+OFF_XMID);
  short *X2=(short*)(ws+OFF_X2);
  short *H1=(short*)(ws+OFF_H1), *H3=(short*)(ws+OFF_H3);
  float *INVT=(float*)(ws+OFF_INVT), *INVR=(float*)(ws+OFF_INVR), *GATES=(float*)(ws+OFF_GATES);

  invtab_kernel<<<1, 64, 0, stream>>>(INVT);
  rmsnorm_kernel<<<4096, 256, 0, stream>>>(x, n1w, X1H, X1L, nullptr);
  // weight transposes: normal layout zso=K*N, ldo=K
  transpose_conv_kernel<true ><<<dim3(32,32,1), 256, 0, stream>>>(wq,   WQTH, WQTL, 1024, 1024, 0, 1024);
  transpose_conv_kernel<true ><<<dim3( 8,32,1), 256, 0, stream>>>(wdkv, WDKVH, WDKVL, 1024, 256, 0, 1024);
  transpose_conv_kernel<true ><<<dim3(32, 8,1), 256, 0, stream>>>(wuk,  WUKH, WUKL, 256, 1024, 0, 256);
  transpose_conv_kernel<true ><<<dim3(32, 8,1), 256, 0, stream>>>(wuv,  WUVH, WUVL, 256, 1024, 0, 256);
  transpose_conv_kernel<true ><<<dim3(32,32,1), 256, 0, stream>>>(wo,   WOTH, WOTL, 1024, 1024, 0, 1024);
  transpose_conv_kernel<false><<<dim3( 8,32,8), 256, 0, stream>>>(w1,   W1T, nullptr, 1024, 256, 262144, 1024);
  transpose_conv_kernel<false><<<dim3( 8,32,8), 256, 0, stream>>>(w3,   W3T, nullptr, 1024, 256, 262144, 1024);
  transpose_conv_kernel<false><<<dim3(32, 8,8), 256, 0, stream>>>(w2,   W2S, nullptr, 256, 1024, 256, 2048); // stacked
  // attention-path split GEMMs
  gemm_split_kernel<0><<<dim3(32,8), 256, 0, stream>>>(X1H, X1L, WQTH, WQTL, QTH, QTL, nullptr, nullptr, 4096, 1024, 1024);
  gemm_split_kernel<0><<<dim3(32,2), 256, 0, stream>>>(X1H, X1L, WDKVH, WDKVL, CH, CL, nullptr, nullptr, 4096, 256, 1024);
  gemm_split_kernel<0><<<dim3(32,8), 256, 0, stream>>>(CH, CL, WUKH, WUKL, KTH, KTL, nullptr, nullptr, 4096, 1024, 256);
  gemm_split_kernel<0><<<dim3(32,8), 256, 0, stream>>>(CH, CL, WUVH, WUVL, VTOKH, VTOKL, nullptr, nullptr, 4096, 1024, 256);
  v_tr_kernel<<<dim3(32,32), 256, 0, stream>>>(VTOKH, VTOKL, VT_H, VT_L);
  rope_inplace_kernel<<<4096, 256, 0, stream>>>(QTH, QTL, KTH, KTL, pos, INVT);
  attn_kernel<<<dim3(32,32), 256, 0, stream>>>(QTH, QTL, KTH, KTL, VT_H, VT_L, AOH, AOL);
  gemm_split_kernel<1><<<dim3(32,8), 256, 0, stream>>>(AOH, AOL, WOTH, WOTL, nullptr, nullptr, XMID, x, 4096, 1024, 1024);
  rmsnorm_kernel<<<4096, 256, 0, stream>>>(XMID, n2w, X2, nullptr, INVR);
  router_kernel<<<4096, 256, 0, stream>>>(XMID, INVR, n2w, wr, rbias, GATES);
  // MoE: h1/h3 token-major stacked [4096][e*256+col]
  gemm_bt_kernel<0><<<dim3(32,2,8), 256, 0, stream>>>(X2, W1T, H1, nullptr, 4096, 256, 1024, 262144, 256, 2048);
  gemm_bt_kernel<0><<<dim3(32,2,8), 256, 0, stream>>>(X2, W3T, H3, nullptr, 4096, 256, 1024, 262144, 256, 2048);
  silu_gate_kernel<<<4096, 256, 0, stream>>>(H1, H3, GATES, H1);
  // out = xmid + h' @ W2S^T   (single stacked GEMM, K=2048)
  gemm_bt_kernel<1><<<dim3(32,8,1), 256, 0, stream>>>(H1, W2S, out, XMID, 4096, 1024, 2048, 0, 0, 0);
}

// Round 9
// 548.264 us; speedup vs baseline: 2.1916x; 1.1023x over previous
//
#include <hip/hip_runtime.h>
#include <hip/hip_bf16.h>
#include <math.h>

// DeepSeekV3-style block: rmsnorm -> MLA attn -> residual -> rmsnorm -> MoE -> residual
// B=2 S=2048 D=1024 H=16 HD=64 R=256 E=8 K=2 MH=256
//
// Precision: attention path in emulated fp32 (bf16 hi/lo pairs, 3-term MFMA) so the
// router top-2 doesn't flip. MoE path plain bf16.
// Attn: causal-paired q-tiles (uniform work/block) + double-buffered K/V staging with
// one barrier per kv-tile (stage(t+1) issued before compute(t); __syncthreads' implicit
// vmcnt(0) drain completes it).

typedef __attribute__((ext_vector_type(8))) short short8;
typedef __attribute__((ext_vector_type(4))) float f32x4;

static __device__ __forceinline__ float bf2f(short s) {
  union { unsigned u; float f; } c; c.u = ((unsigned)(unsigned short)s) << 16; return c.f;
}
static __device__ __forceinline__ short f2bf(float f) {
  __hip_bfloat16 h = __float2bfloat16(f);
  short s; __builtin_memcpy(&s, &h, sizeof(s)); return s;
}
static __device__ __forceinline__ void split2(float v, short& hi, short& lo) {
  hi = f2bf(v); lo = f2bf(v - bf2f(hi));
}
#define GLD16(gp, lp) __builtin_amdgcn_global_load_lds( \
    (__attribute__((address_space(1))) void*)(gp), \
    (__attribute__((address_space(3))) void*)(lp), 16, 0, 0)

// ---------------- RoPE inv-freq table, bit-faithful to numpy f32 -------------------------
__global__ void invtab_kernel(float* __restrict__ tab) {
  int j = threadIdx.x;
  if (j < 32) {
    float t = (float)pow(10000.0, (double)j * (1.0 / 32.0));
    tab[j] = 1.0f / t;
  }
}

// ---------------- rmsnorm: f32 in -> bf16 hi (+optional lo) ------------------------------
__global__ __launch_bounds__(256) void rmsnorm_kernel(
    const float* __restrict__ in, const float* __restrict__ w,
    short* __restrict__ outH, short* __restrict__ outL)
{
  int row = blockIdx.x, tid = threadIdx.x;
  const float4* xv = (const float4*)(in + (size_t)row * 1024);
  float4 v = xv[tid];
  float ss = v.x*v.x + v.y*v.y + v.z*v.z + v.w*v.w;
  #pragma unroll
  for (int off = 32; off > 0; off >>= 1) ss += __shfl_down(ss, off);
  __shared__ float wsum[4];
  if ((tid & 63) == 0) wsum[tid >> 6] = ss;
  __syncthreads();
  float inv = rsqrtf((wsum[0] + wsum[1] + wsum[2] + wsum[3]) * (1.0f/1024.0f) + 1e-6f);
  float4 wv = ((const float4*)w)[tid];
  size_t base = (size_t)row * 1024 + (size_t)tid * 4;
  float r[4] = { v.x*inv*wv.x, v.y*inv*wv.y, v.z*inv*wv.z, v.w*inv*wv.w };
  #pragma unroll
  for (int j = 0; j < 4; ++j) {
    short hi, lo; split2(r[j], hi, lo);
    outH[base + j] = hi;
    if (outL) outL[base + j] = lo;
  }
}

// ---------------- fused rmsnorm2 + router (bf16 X2 + top-2 gates) ------------------------
__global__ __launch_bounds__(256) void rmsnorm_router_kernel(
    const float* __restrict__ in, const float* __restrict__ w,
    short* __restrict__ outH,
    const float* __restrict__ wr, const float* __restrict__ rbias,
    float* __restrict__ gates)
{
  int row = blockIdx.x, tid = threadIdx.x;
  float4 v = ((const float4*)(in + (size_t)row * 1024))[tid];
  float ss = v.x*v.x + v.y*v.y + v.z*v.z + v.w*v.w;
  #pragma unroll
  for (int off = 32; off > 0; off >>= 1) ss += __shfl_down(ss, off);
  __shared__ float wsum[4];
  if ((tid & 63) == 0) wsum[tid >> 6] = ss;
  __syncthreads();
  float inv = rsqrtf((wsum[0] + wsum[1] + wsum[2] + wsum[3]) * (1.0f/1024.0f) + 1e-6f);
  float4 wv = ((const float4*)w)[tid];
  size_t base = (size_t)row * 1024 + (size_t)tid * 4;
  float r[4] = { v.x*inv*wv.x, v.y*inv*wv.y, v.z*inv*wv.z, v.w*inv*wv.w };
  #pragma unroll
  for (int j = 0; j < 4; ++j) outH[base + j] = f2bf(r[j]);
  // router partials on the exact f32 normalized values
  float part[8] = {0,0,0,0,0,0,0,0};
  const float* wrp = wr + (size_t)tid * 32;       // rows tid*4 .. tid*4+3, 8 cols each
  #pragma unroll
  for (int j = 0; j < 4; ++j)
    #pragma unroll
    for (int e = 0; e < 8; ++e) part[e] += r[j] * wrp[j * 8 + e];
  #pragma unroll
  for (int e = 0; e < 8; ++e)
    #pragma unroll
    for (int off = 32; off > 0; off >>= 1) part[e] += __shfl_down(part[e], off);
  __shared__ float red[4][8];
  if ((tid & 63) == 0)
    #pragma unroll
    for (int e = 0; e < 8; ++e) red[tid >> 6][e] = part[e];
  __syncthreads();
  if (tid == 0) {
    float sc[8], bs[8];
    #pragma unroll
    for (int e = 0; e < 8; ++e) {
      float t = red[0][e] + red[1][e] + red[2][e] + red[3][e];
      sc[e] = 1.f / (1.f + expf(-t));
      bs[e] = sc[e] + rbias[e];
    }
    int i0 = 0;
    #pragma unroll
    for (int e = 1; e < 8; ++e) if (bs[e] > bs[i0]) i0 = e;   // ties -> lowest idx
    int i1 = -1;
    #pragma unroll
    for (int e = 0; e < 8; ++e) if (e != i0 && (i1 < 0 || bs[e] > bs[i1])) i1 = e;
    float s0 = sc[i0], s1 = sc[i1];
    float den = s0 + s1 + 1e-9f;
    #pragma unroll
    for (int e = 0; e < 8; ++e)
      gates[(size_t)row * 8 + e] = (e == i0) ? s0 / den : ((e == i1) ? s1 / den : 0.f);
  }
}

// ---------------- transpose+convert: f32 (K,N) -> bf16, generalized out layout -----------
// out index = z*zso + n*ldo + k.  Normal: zso=K*N, ldo=K.  W2-stacked: zso=256, ldo=2048.
template<bool SPLIT>
__global__ __launch_bounds__(256) void transpose_conv_kernel(
    const float* __restrict__ in, short* __restrict__ outH, short* __restrict__ outL,
    int K, int N, long zso, long ldo)
{
  __shared__ float tile[32][33];
  const float* ip = in + (size_t)blockIdx.z * K * N;
  size_t ob = (size_t)blockIdx.z * zso;
  int bn = blockIdx.x * 32, bk = blockIdx.y * 32;
  int tx = threadIdx.x & 31, ty = threadIdx.x >> 5;
  #pragma unroll
  for (int i = 0; i < 32; i += 8)
    tile[ty + i][tx] = ip[(size_t)(bk + ty + i) * N + bn + tx];
  __syncthreads();
  #pragma unroll
  for (int i = 0; i < 32; i += 8) {
    float v = tile[tx][ty + i];
    size_t oi = ob + (size_t)(bn + ty + i) * ldo + bk + tx;
    short hi, lo; split2(v, hi, lo);
    outH[oi] = hi;
    if (SPLIT) outL[oi] = lo;
  }
}

// ---------------- split GEMM: C = (AH+AL)[M,K] @ (BH+BL)[N,K]^T, 3-term emulated f32 -----
template<int EPI>
__global__ __launch_bounds__(256) void gemm_split_kernel(
    const short* __restrict__ AH, const short* __restrict__ AL,
    const short* __restrict__ BH, const short* __restrict__ BL,
    short* __restrict__ CH, short* __restrict__ CL,
    float* __restrict__ Cf, const float* __restrict__ res,
    int M, int N, int K)
{
  __shared__ __align__(16) short AsH[128*32], AsL[128*32], BsH[128*32], BsL[128*32];
  int bm = blockIdx.x * 128, bn = blockIdx.y * 128;
  int tid = threadIdx.x;
  int wave = tid >> 6, lane = tid & 63;
  int g = lane >> 4, r16 = lane & 15;
  int wr = wave >> 1, wc = wave & 1;
  f32x4 acc[4][4];
  #pragma unroll
  for (int m = 0; m < 4; ++m)
    #pragma unroll
    for (int n = 0; n < 4; ++n) acc[m][n] = (f32x4){0.f,0.f,0.f,0.f};
  int flat0 = tid * 8;
  for (int k0 = 0; k0 < K; k0 += 32) {
    __syncthreads();
    #pragma unroll
    for (int it = 0; it < 2; ++it) {
      int flat = it * 2048 + flat0;
      int row = flat >> 5, col = flat & 31;
      size_t ga = (size_t)(bm + row) * K + k0 + col;
      size_t gb = (size_t)(bn + row) * K + k0 + col;
      int lo = it * 4096 + wave * 1024;
      GLD16(AH + ga, (char*)AsH + lo);
      GLD16(AL + ga, (char*)AsL + lo);
      GLD16(BH + gb, (char*)BsH + lo);
      GLD16(BL + gb, (char*)BsL + lo);
    }
    __syncthreads();
    short8 afh[4], afl[4], bfh[4], bfl[4];
    #pragma unroll
    for (int m = 0; m < 4; ++m) {
      int off = (64*wr + 16*m + r16) * 32 + g * 8;
      afh[m] = *(const short8*)(AsH + off);
      afl[m] = *(const short8*)(AsL + off);
    }
    #pragma unroll
    for (int n = 0; n < 4; ++n) {
      int off = (64*wc + 16*n + r16) * 32 + g * 8;
      bfh[n] = *(const short8*)(BsH + off);
      bfl[n] = *(const short8*)(BsL + off);
    }
    #pragma unroll
    for (int m = 0; m < 4; ++m)
      #pragma unroll
      for (int n = 0; n < 4; ++n) {
        acc[m][n] = __builtin_amdgcn_mfma_f32_16x16x32_bf16(afh[m], bfh[n], acc[m][n], 0, 0, 0);
        acc[m][n] = __builtin_amdgcn_mfma_f32_16x16x32_bf16(afh[m], bfl[n], acc[m][n], 0, 0, 0);
        acc[m][n] = __builtin_amdgcn_mfma_f32_16x16x32_bf16(afl[m], bfh[n], acc[m][n], 0, 0, 0);
      }
  }
  #pragma unroll
  for (int m = 0; m < 4; ++m)
    #pragma unroll
    for (int n = 0; n < 4; ++n)
      #pragma unroll
      for (int r = 0; r < 4; ++r) {
        int row = bm + 64*wr + 16*m + g*4 + r;
        int col = bn + 64*wc + 16*n + r16;
        size_t idx = (size_t)row * N + col;
        float v = acc[m][n][r];
        if (EPI == 0) {
          short hi, lo; split2(v, hi, lo);
          CH[idx] = hi; CL[idx] = lo;
        } else {
          Cf[idx] = v + res[idx];
        }
      }
}

// ---------------- plain bf16 GEMM (MoE path) ---------------------------------------------
// EPI 0: bf16 store at z*sC + row*ldC + col.
// EPI 1: f32 C = acc + res (z==1, N==ldC).
// EPI 2: h' = gates[row,z] * silu(aux[oi]) * acc, bf16 store at oi (fused silu-gate).
template<int EPI>
__global__ __launch_bounds__(256) void gemm_bt_kernel(
    const short* __restrict__ A, const short* __restrict__ Bt, void* __restrict__ Cv,
    const float* __restrict__ res, const short* __restrict__ aux,
    const float* __restrict__ gates,
    int M, int N, int K, long sBt, long sC, long ldC)
{
  __shared__ __align__(16) short As[128*32];
  __shared__ __align__(16) short Bs[128*32];
  int z = blockIdx.z;
  const short* Ab = A;
  const short* Bb = Bt + (size_t)z * sBt;
  int bm = blockIdx.x * 128, bn = blockIdx.y * 128;
  int tid = threadIdx.x;
  int wave = tid >> 6, lane = tid & 63;
  int g = lane >> 4, r16 = lane & 15;
  int wr = wave >> 1, wc = wave & 1;
  f32x4 acc[4][4];
  #pragma unroll
  for (int m = 0; m < 4; ++m)
    #pragma unroll
    for (int n = 0; n < 4; ++n) acc[m][n] = (f32x4){0.f,0.f,0.f,0.f};
  int flat0 = tid * 8;
  for (int k0 = 0; k0 < K; k0 += 32) {
    __syncthreads();
    #pragma unroll
    for (int it = 0; it < 2; ++it) {
      int flat = it * 2048 + flat0;
      int row = flat >> 5, col = flat & 31;
      GLD16(Ab + (size_t)(bm + row) * K + k0 + col, (char*)As + it * 4096 + wave * 1024);
      GLD16(Bb + (size_t)(bn + row) * K + k0 + col, (char*)Bs + it * 4096 + wave * 1024);
    }
    __syncthreads();
    short8 af[4], bfv[4];
    #pragma unroll
    for (int m = 0; m < 4; ++m)
      af[m] = *(const short8*)(As + (64*wr + 16*m + r16) * 32 + g * 8);
    #pragma unroll
    for (int n = 0; n < 4; ++n)
      bfv[n] = *(const short8*)(Bs + (64*wc + 16*n + r16) * 32 + g * 8);
    #pragma unroll
    for (int m = 0; m < 4; ++m)
      #pragma unroll
      for (int n = 0; n < 4; ++n)
        acc[m][n] = __builtin_amdgcn_mfma_f32_16x16x32_bf16(af[m], bfv[n], acc[m][n], 0, 0, 0);
  }
  #pragma unroll
  for (int m = 0; m < 4; ++m)
    #pragma unroll
    for (int n = 0; n < 4; ++n)
      #pragma unroll
      for (int r = 0; r < 4; ++r) {
        int row = bm + 64*wr + 16*m + g*4 + r;
        int col = bn + 64*wc + 16*n + r16;
        float v = acc[m][n][r];
        if (EPI == 0) {
          ((short*)Cv)[(size_t)z * sC + (size_t)row * ldC + col] = f2bf(v);
        } else if (EPI == 1) {
          size_t idx = (size_t)row * N + col;
          ((float*)Cv)[idx] = v + res[idx];
        } else {
          size_t oi = (size_t)z * sC + (size_t)row * ldC + col;
          float xv = bf2f(aux[oi]);
          float gv = gates[(size_t)row * 8 + z];
          ((short*)Cv)[oi] = f2bf(gv * (xv / (1.f + expf(-xv))) * v);
        }
      }
}

// ---------------- RoPE in-place on split q,k (token-major B,S,H,HD) ----------------------
__global__ __launch_bounds__(256) void rope_inplace_kernel(
    short* __restrict__ QH, short* __restrict__ QL,
    short* __restrict__ KH, short* __restrict__ KL,
    const int* __restrict__ pos_ids, const float* __restrict__ invtab)
{
  int token = blockIdx.x, tid = threadIdx.x;
  float pos = (float)pos_ids[token];
  #pragma unroll
  for (int it = 0; it < 2; ++it) {
    int p = it * 256 + tid;
    int h = p >> 5, j = p & 31;
    float ang = pos * invtab[j];
    float sn, cs; sincosf(ang, &sn, &cs);
    size_t i1 = (size_t)token * 1024 + h * 64 + j;
    size_t i2 = i1 + 32;
    float q1 = bf2f(QH[i1]) + bf2f(QL[i1]);
    float q2 = bf2f(QH[i2]) + bf2f(QL[i2]);
    float a = q1 * cs - q2 * sn, bq = q1 * sn + q2 * cs;
    short hi, lo;
    split2(a,  hi, lo); QH[i1] = hi; QL[i1] = lo;
    split2(bq, hi, lo); QH[i2] = hi; QL[i2] = lo;
    float k1 = bf2f(KH[i1]) + bf2f(KL[i1]);
    float k2 = bf2f(KH[i2]) + bf2f(KL[i2]);
    a = k1 * cs - k2 * sn; bq = k1 * sn + k2 * cs;
    split2(a,  hi, lo); KH[i1] = hi; KL[i1] = lo;
    split2(bq, hi, lo); KH[i2] = hi; KL[i2] = lo;
  }
}

// ---------------- V transpose: token-major (b,s,h,d) -> VT[bh][d=64][s=2048] -------------
__global__ __launch_bounds__(256) void v_tr_kernel(
    const short* __restrict__ VH, const short* __restrict__ VL,
    short* __restrict__ TH, short* __restrict__ TL)
{
  __shared__ short th[64][80], tl[64][80];
  int s0 = blockIdx.x * 64, bh = blockIdx.y;
  int b = bh >> 4, h = bh & 15;
  int tid = threadIdx.x;
  #pragma unroll
  for (int p = 0; p < 2; ++p) {
    int flat = p * 256 + tid;
    int sr = flat >> 3, ck = flat & 7;
    size_t gi = ((size_t)((b * 2048) + s0 + sr) * 16 + h) * 64 + ck * 8;
    short8 vh = *(const short8*)(VH + gi);
    short8 vl = *(const short8*)(VL + gi);
    #pragma unroll
    for (int i = 0; i < 8; ++i) { th[sr][ck*8+i] = vh[i]; tl[sr][ck*8+i] = vl[i]; }
  }
  __syncthreads();
  #pragma unroll
  for (int p = 0; p < 2; ++p) {
    int flat = p * 256 + tid;
    int dr = flat >> 3, sc = flat & 7;
    short8 rh, rl;
    #pragma unroll
    for (int i = 0; i < 8; ++i) { rh[i] = th[sc*8+i][dr]; rl[i] = tl[sc*8+i][dr]; }
    size_t go = ((size_t)bh * 64 + dr) * 2048 + s0 + sc * 8;
    *(short8*)(TH + go) = rh;
    *(short8*)(TL + go) = rl;
  }
}

// ---------------- causal flash attention, split precision, paired q-tiles ----------------
// Block bx handles q-tile (31-bx) then (bx): uniform 33-34 kv-tiles per block.
// Double-buffered K/V LDS; stage(t+1) issued before compute(t); one barrier/tile.
__global__ __launch_bounds__(256) void attn_kernel(
    const short* __restrict__ QH, const short* __restrict__ QL,
    const short* __restrict__ KH, const short* __restrict__ KL,
    const short* __restrict__ VTH, const short* __restrict__ VTL,
    short* __restrict__ OH, short* __restrict__ OL)
{
  __shared__ __align__(16) char ksH[2][8192], ksL[2][8192], vtH[2][8192], vtL[2][8192];
  int bx = blockIdx.x;                       // 0..15
  int bh = blockIdx.y;
  int b = bh >> 4, h = bh & 15;
  int tid = threadIdx.x;
  int w = tid >> 6, lane = tid & 63;
  int g = lane >> 4, r16 = lane & 15;
  auto gidx = [&](int s, int d) -> size_t {
    return ((size_t)(b * 2048 + s) * 16 + h) * 64 + d;
  };
  int srow = lane >> 3, cs0 = lane & 7;
  auto stage = [&](int t, int buf) {
    int kvb = t * 64;
    #pragma unroll
    for (int i = 0; i < 2; ++i) {
      int wi = w * 2 + i;
      int row = wi * 8 + srow;
      int cs = cs0 ^ (row & 7);              // inverse-swizzled source chunk
      size_t gk = gidx(kvb + row, cs * 8);
      size_t gv = ((size_t)bh * 64 + row) * 2048 + kvb + cs * 8;
      int lb = wi * 1024;
      GLD16(KH + gk,  &ksH[buf][lb]);
      GLD16(KL + gk,  &ksL[buf][lb]);
      GLD16(VTH + gv, &vtH[buf][lb]);
      GLD16(VTL + gv, &vtL[buf][lb]);
    }
  };
  for (int half = 0; half < 2; ++half) {
    int qt = half ? bx : (31 - bx);
    int qb = qt * 64;
    int qrow = qb + 16 * w + r16;
    short8 qf0h = *(const short8*)(QH + gidx(qrow, g * 8));
    short8 qf0l = *(const short8*)(QL + gidx(qrow, g * 8));
    short8 qf1h = *(const short8*)(QH + gidx(qrow, 32 + g * 8));
    short8 qf1l = *(const short8*)(QL + gidx(qrow, 32 + g * 8));
    f32x4 o[4];
    #pragma unroll
    for (int c = 0; c < 4; ++c) o[c] = (f32x4){0.f,0.f,0.f,0.f};
    float mrun = -1e30f, lsum = 0.f;
    int qi = qrow;
    int nt = qt + 1;
    int cur = 0;
    stage(0, cur);
    for (int t = 0; t < nt; ++t) {
      __syncthreads();                       // stage(t) drained + prior LDS reads done
      if (t + 1 < nt) stage(t + 1, cur ^ 1); // overlap next staging with compute
      int kvb = t * 64;
      float p16[16]; float tm = -1e30f;
      #pragma unroll
      for (int T = 0; T < 4; ++T) {          // S^T tile 16kv x 16q, K=64 split
        int krow = 16 * T + r16;
        int swz = (r16 & 7) << 4;
        short8 k0h = *(const short8*)(&ksH[cur][krow * 128 + ((16 * g) ^ swz)]);
        short8 k0l = *(const short8*)(&ksL[cur][krow * 128 + ((16 * g) ^ swz)]);
        short8 k1h = *(const short8*)(&ksH[cur][krow * 128 + ((64 + 16 * g) ^ swz)]);
        short8 k1l = *(const short8*)(&ksL[cur][krow * 128 + ((64 + 16 * g) ^ swz)]);
        f32x4 a = (f32x4){0.f,0.f,0.f,0.f};
        a = __builtin_amdgcn_mfma_f32_16x16x32_bf16(k0h, qf0h, a, 0, 0, 0);
        a = __builtin_amdgcn_mfma_f32_16x16x32_bf16(k0h, qf0l, a, 0, 0, 0);
        a = __builtin_amdgcn_mfma_f32_16x16x32_bf16(k0l, qf0h, a, 0, 0, 0);
        a = __builtin_amdgcn_mfma_f32_16x16x32_bf16(k1h, qf1h, a, 0, 0, 0);
        a = __builtin_amdgcn_mfma_f32_16x16x32_bf16(k1h, qf1l, a, 0, 0, 0);
        a = __builtin_amdgcn_mfma_f32_16x16x32_bf16(k1l, qf1h, a, 0, 0, 0);
        #pragma unroll
        for (int r = 0; r < 4; ++r) {
          float sv = a[r] * 0.125f;          // 1/sqrt(64)
          int kvi = kvb + 16 * T + 4 * g + r;
          sv = (kvi > qi) ? -1e30f : sv;     // causal
          p16[T * 4 + r] = sv;
          tm = fmaxf(tm, sv);
        }
      }
      tm = fmaxf(tm, __shfl_xor(tm, 16));
      tm = fmaxf(tm, __shfl_xor(tm, 32));
      float mnew = fmaxf(mrun, tm);
      float sf = __expf(mrun - mnew);
      float ps = 0.f;
      #pragma unroll
      for (int i2 = 0; i2 < 16; ++i2) { p16[i2] = __expf(p16[i2] - mnew); ps += p16[i2]; }
      ps += __shfl_xor(ps, 16);
      ps += __shfl_xor(ps, 32);
      lsum = lsum * sf + ps;
      mrun = mnew;
      float sfr[4];
      #pragma unroll
      for (int r = 0; r < 4; ++r) sfr[r] = __shfl(sf, 4 * g + r);
      #pragma unroll
      for (int c = 0; c < 4; ++c)
        #pragma unroll
        for (int r = 0; r < 4; ++r) o[c][r] *= sfr[r];
      // P^T -> P A-frags (kv halves), split hi/lo
      short8 pah[2], pal[2];
      #pragma unroll
      for (int h2 = 0; h2 < 2; ++h2) {
        #pragma unroll
        for (int j = 0; j < 8; ++j) {
          int src = (((2 * g + (j >> 2)) & 3) << 4) + r16;
          float v0 = __shfl(p16[(2 * h2) * 4 + (j & 3)], src);
          float v1 = __shfl(p16[(2 * h2 + 1) * 4 + (j & 3)], src);
          float pv = (g >= 2) ? v1 : v0;
          short phi, plo; split2(pv, phi, plo);
          pah[h2][j] = phi; pal[h2][j] = plo;
        }
      }
      #pragma unroll
      for (int c = 0; c < 4; ++c) {          // O[q,d] += P @ V via VT b128 reads
        #pragma unroll
        for (int h2 = 0; h2 < 2; ++h2) {
          int bo = (16 * c + r16) * 128 + ((64 * h2 + 16 * g) ^ ((r16 & 7) << 4));
          short8 vbh = *(const short8*)(&vtH[cur][bo]);
          short8 vbl = *(const short8*)(&vtL[cur][bo]);
          o[c] = __builtin_amdgcn_mfma_f32_16x16x32_bf16(pah[h2], vbh, o[c], 0, 0, 0);
          o[c] = __builtin_amdgcn_mfma_f32_16x16x32_bf16(pah[h2], vbl, o[c], 0, 0, 0);
          o[c] = __builtin_amdgcn_mfma_f32_16x16x32_bf16(pal[h2], vbh, o[c], 0, 0, 0);
        }
      }
      cur ^= 1;
    }
    float lr[4];
    #pragma unroll
    for (int r = 0; r < 4; ++r) lr[r] = __shfl(lsum, 4 * g + r);
    #pragma unroll
    for (int c = 0; c < 4; ++c)
      #pragma unroll
      for (int r = 0; r < 4; ++r) {
        int q = qb + 16 * w + 4 * g + r;
        int d = 16 * c + r16;
        float v = o[c][r] / lr[r];
        short hi, lo; split2(v, hi, lo);
        size_t oi = gidx(q, d);
        OH[oi] = hi; OL[oi] = lo;
      }
  }
}

// ---------------- workspace layout (1 MB = 1048576 B) ------------------------------------
#define MB (1048576ull)
enum : unsigned long long {
  OFF_WQTH  = 0*MB,  OFF_WQTL  = 2*MB,
  OFF_WDKVH = 4*MB,  OFF_WDKVL = 4*MB + 512*1024,
  OFF_WUKH  = 5*MB,  OFF_WUKL  = 5*MB + 512*1024,
  OFF_WUVH  = 6*MB,  OFF_WUVL  = 6*MB + 512*1024,
  OFF_WOTH  = 7*MB,  OFF_WOTL  = 9*MB,
  OFF_W1T   = 11*MB, OFF_W3T   = 15*MB, OFF_W2S = 19*MB,   // W2S: [1024][e*256+k] 4MB
  OFF_X1H   = 23*MB, OFF_X1L   = 31*MB,
  OFF_QTH   = 39*MB, OFF_QTL   = 47*MB,
  OFF_CH    = 55*MB, OFF_CL    = 57*MB,
  OFF_KTH   = 59*MB, OFF_KTL   = 67*MB,
  OFF_VTOKH = 75*MB, OFF_VTOKL = 83*MB,
  // aliases (time-disjoint):
  OFF_VT_H  = 23*MB, OFF_VT_L  = 31*MB,          // V^T (X1 dead after q/c gemms)
  OFF_AOH   = 75*MB, OFF_AOL   = 83*MB,          // attn out (VTOK dead after v_tr)
  OFF_XMID  = 39*MB,                             // f32 16MB (QT dead after attn); live to end
  OFF_X2    = 55*MB,                             // bf16 8MB (C dead, KTH head dead after attn)
  OFF_H1    = 23*MB,                             // [4096][2048] bf16 16MB (VT dead after attn)
  OFF_H3    = 75*MB,                             // [4096][2048] bf16 16MB (AO dead after wo gemm)
  OFF_INVT  = 91*MB,
  OFF_GATES = 91*MB + 32768,
  WS_NEEDED = 91*MB + 262144
};

extern "C" void kernel_launch(void* const* d_in, const int* in_sizes, int n_in,
                              void* d_out, int out_size, void* d_ws, size_t ws_size,
                              hipStream_t stream) {
  const float* x     = (const float*)d_in[0];
  const int*   pos   = (const int*)d_in[1];
  const float* n1w   = (const float*)d_in[2];
  const float* wq    = (const float*)d_in[3];
  const float* wdkv  = (const float*)d_in[4];
  const float* wuk   = (const float*)d_in[5];
  const float* wuv   = (const float*)d_in[6];
  const float* wo    = (const float*)d_in[7];
  const float* n2w   = (const float*)d_in[8];
  const float* wr    = (const float*)d_in[9];
  const float* rbias = (const float*)d_in[10];
  const float* w1    = (const float*)d_in[11];
  const float* w3    = (const float*)d_in[12];
  const float* w2    = (const float*)d_in[13];
  float* out = (float*)d_out;
  char* ws = (char*)d_ws;
  if (ws_size < WS_NEEDED) return;

  short *WQTH=(short*)(ws+OFF_WQTH), *WQTL=(short*)(ws+OFF_WQTL);
  short *WDKVH=(short*)(ws+OFF_WDKVH), *WDKVL=(short*)(ws+OFF_WDKVL);
  short *WUKH=(short*)(ws+OFF_WUKH), *WUKL=(short*)(ws+OFF_WUKL);
  short *WUVH=(short*)(ws+OFF_WUVH), *WUVL=(short*)(ws+OFF_WUVL);
  short *WOTH=(short*)(ws+OFF_WOTH), *WOTL=(short*)(ws+OFF_WOTL);
  short *W1T=(short*)(ws+OFF_W1T), *W3T=(short*)(ws+OFF_W3T), *W2S=(short*)(ws+OFF_W2S);
  short *X1H=(short*)(ws+OFF_X1H), *X1L=(short*)(ws+OFF_X1L);
  short *QTH=(short*)(ws+OFF_QTH), *QTL=(short*)(ws+OFF_QTL);
  short *CH=(short*)(ws+OFF_CH),   *CL=(short*)(ws+OFF_CL);
  short *KTH=(short*)(ws+OFF_KTH), *KTL=(short*)(ws+OFF_KTL);
  short *VTOKH=(short*)(ws+OFF_VTOKH), *VTOKL=(short*)(ws+OFF_VTOKL);
  short *VT_H=(short*)(ws+OFF_VT_H), *VT_L=(short*)(ws+OFF_VT_L);
  short *AOH=(short*)(ws+OFF_AOH), *AOL=(short*)(ws+OFF_AOL);
  float *XMID=(float*)(ws+OFF_XMID);
  short *X2=(short*)(ws+OFF_X2);
  short *H1=(short*)(ws+OFF_H1), *H3=(short*)(ws+OFF_H3);
  float *INVT=(float*)(ws+OFF_INVT), *GATES=(float*)(ws+OFF_GATES);

  invtab_kernel<<<1, 64, 0, stream>>>(INVT);
  rmsnorm_kernel<<<4096, 256, 0, stream>>>(x, n1w, X1H, X1L);
  // weight transposes
  transpose_conv_kernel<true ><<<dim3(32,32,1), 256, 0, stream>>>(wq,   WQTH, WQTL, 1024, 1024, 0, 1024);
  transpose_conv_kernel<true ><<<dim3( 8,32,1), 256, 0, stream>>>(wdkv, WDKVH, WDKVL, 1024, 256, 0, 1024);
  transpose_conv_kernel<true ><<<dim3(32, 8,1), 256, 0, stream>>>(wuk,  WUKH, WUKL, 256, 1024, 0, 256);
  transpose_conv_kernel<true ><<<dim3(32, 8,1), 256, 0, stream>>>(wuv,  WUVH, WUVL, 256, 1024, 0, 256);
  transpose_conv_kernel<true ><<<dim3(32,32,1), 256, 0, stream>>>(wo,   WOTH, WOTL, 1024, 1024, 0, 1024);
  transpose_conv_kernel<false><<<dim3( 8,32,8), 256, 0, stream>>>(w1,   W1T, nullptr, 1024, 256, 262144, 1024);
  transpose_conv_kernel<false><<<dim3( 8,32,8), 256, 0, stream>>>(w3,   W3T, nullptr, 1024, 256, 262144, 1024);
  transpose_conv_kernel<false><<<dim3(32, 8,8), 256, 0, stream>>>(w2,   W2S, nullptr, 256, 1024, 256, 2048);
  // attention-path split GEMMs
  gemm_split_kernel<0><<<dim3(32,8), 256, 0, stream>>>(X1H, X1L, WQTH, WQTL, QTH, QTL, nullptr, nullptr, 4096, 1024, 1024);
  gemm_split_kernel<0><<<dim3(32,2), 256, 0, stream>>>(X1H, X1L, WDKVH, WDKVL, CH, CL, nullptr, nullptr, 4096, 256, 1024);
  gemm_split_kernel<0><<<dim3(32,8), 256, 0, stream>>>(CH, CL, WUKH, WUKL, KTH, KTL, nullptr, nullptr, 4096, 1024, 256);
  gemm_split_kernel<0><<<dim3(32,8), 256, 0, stream>>>(CH, CL, WUVH, WUVL, VTOKH, VTOKL, nullptr, nullptr, 4096, 1024, 256);
  v_tr_kernel<<<dim3(32,32), 256, 0, stream>>>(VTOKH, VTOKL, VT_H, VT_L);
  rope_inplace_kernel<<<4096, 256, 0, stream>>>(QTH, QTL, KTH, KTL, pos, INVT);
  attn_kernel<<<dim3(16,32), 256, 0, stream>>>(QTH, QTL, KTH, KTL, VT_H, VT_L, AOH, AOL);
  gemm_split_kernel<1><<<dim3(32,8), 256, 0, stream>>>(AOH, AOL, WOTH, WOTL, nullptr, nullptr, XMID, x, 4096, 1024, 1024);
  // fused rmsnorm2 + router
  rmsnorm_router_kernel<<<4096, 256, 0, stream>>>(XMID, n2w, X2, wr, rbias, GATES);
  // MoE: h1 GEMM, then h3 GEMM with fused gate*silu(h1)*h3 epilogue
  gemm_bt_kernel<0><<<dim3(32,2,8), 256, 0, stream>>>(X2, W1T, H1, nullptr, nullptr, nullptr, 4096, 256, 1024, 262144, 256, 2048);
  gemm_bt_kernel<2><<<dim3(32,2,8), 256, 0, stream>>>(X2, W3T, H3, nullptr, H1, GATES, 4096, 256, 1024, 262144, 256, 2048);
  // out = xmid + h' @ W2S^T   (single stacked GEMM, K=2048)
  gemm_bt_kernel<1><<<dim3(32,8,1), 256, 0, stream>>>(H3, W2S, out, XMID, nullptr, nullptr, 4096, 1024, 2048, 0, 0, 0);
}